// Round 8
// baseline (705.085 us; speedup 1.0000x reference)
//
#include <hip/hip_runtime.h>
#include <hip/hip_bf16.h>
#include <cstdint>
#include <cstddef>

// ---------------- constants ----------------
#define S_LEN  2048
#define HIDDEN 2304
#define NHEAD  8
#define NKVH   4
#define DHEAD  256
#define FFDIM  9216
#define QKVN   4096   // (H + 2*KV) * D
#define ODIM   2048   // H * D
#define WINM1  1023
#define QSCALE 0.0625f
#define CAPF   50.0f
#define PSTR   ((size_t)S_LEN * HIDDEN)   // partial-plane stride (elements)

typedef __attribute__((ext_vector_type(4))) float f32x4;
typedef __attribute__((ext_vector_type(8))) short s16x8;

// async global->LDS 16B copy; lptr must be wave-uniform, HW adds lane*16
__device__ __forceinline__ void gload_lds16(const void* gptr, void* lptr) {
  __builtin_amdgcn_global_load_lds(
      (const __attribute__((address_space(1))) unsigned int*)gptr,
      (__attribute__((address_space(3))) unsigned int*)lptr, 16, 0, 0);
}

// ---------------- diagnostic fill (ws too small): value encodes ws MiB ----------------
__global__ void k_fill(float* p, float v, size_t n) {
  size_t i = (size_t)blockIdx.x * blockDim.x + threadIdx.x;
  size_t st = (size_t)gridDim.x * blockDim.x;
  for (; i < n; i += st) p[i] = v;
}

// ---------------- f32 [R][C] -> bf16 [C][R] ----------------
__global__ void k_transpose_bf16(const float* __restrict__ in, __hip_bfloat16* __restrict__ out,
                                 int R, int C) {
  __shared__ float tile[32][33];
  const int c0 = blockIdx.x * 32, r0 = blockIdx.y * 32;
  const int tc = threadIdx.x & 31, tr = threadIdx.x >> 5;  // 32 x 8
#pragma unroll
  for (int i = 0; i < 4; i++)
    tile[tr + 8 * i][tc] = in[(size_t)(r0 + tr + 8 * i) * C + c0 + tc];
  __syncthreads();
#pragma unroll
  for (int i = 0; i < 4; i++)
    out[(size_t)(c0 + tr + 8 * i) * R + r0 + tc] = __float2bfloat16(tile[tc][tr + 8 * i]);
}

// ------ rmsnorm over sum of NP planes (plane stride PSTR); optional residual; f32/bf16 out ------
template <int NP, bool INBF16, bool ADD, bool BF16OUT>
__global__ void k_rmsnorm(const void* __restrict__ xv, const float* __restrict__ w,
                          const float* __restrict__ res, void* __restrict__ outv) {
  const int row = blockIdx.x;
  __shared__ float xs[HIDDEN];
  float ss = 0.f;
  for (int i = threadIdx.x; i < HIDDEN; i += 256) {
    float v = 0.f;
#pragma unroll
    for (int p = 0; p < NP; p++) {
      if constexpr (INBF16)
        v += __bfloat162float(((const __hip_bfloat16*)xv)[(size_t)p * PSTR + (size_t)row * HIDDEN + i]);
      else
        v += ((const float*)xv)[(size_t)p * PSTR + (size_t)row * HIDDEN + i];
    }
    xs[i] = v;
    ss += v * v;
  }
#pragma unroll
  for (int off = 32; off >= 1; off >>= 1) ss += __shfl_down(ss, off);
  __shared__ float red[4];
  __shared__ float srstd;
  if ((threadIdx.x & 63) == 0) red[threadIdx.x >> 6] = ss;
  __syncthreads();
  if (threadIdx.x == 0) {
    float tot = red[0] + red[1] + red[2] + red[3];
    srstd = rsqrtf(tot / (float)HIDDEN + 1e-6f);
  }
  __syncthreads();
  const float rstd = srstd;
  for (int i = threadIdx.x; i < HIDDEN; i += 256) {
    float v = xs[i] * rstd * (1.f + w[i]);
    if constexpr (ADD) v += res[(size_t)row * HIDDEN + i];
    if constexpr (BF16OUT)
      ((__hip_bfloat16*)outv)[(size_t)row * HIDDEN + i] = __float2bfloat16(v);
    else
      ((float*)outv)[(size_t)row * HIDDEN + i] = v;
  }
}

// ---- fused: h = res + rmsnorm(P0+P1)*(1+w1) -> Hf(f32); x2 = rmsnorm(h)*(1+w2) -> Xb(bf16) ----
__global__ void k_rmsnorm2(const float* __restrict__ planes, const float* __restrict__ w1,
                           const float* __restrict__ res, const float* __restrict__ w2,
                           float* __restrict__ hf, __hip_bfloat16* __restrict__ xb) {
  const int row = blockIdx.x;
  __shared__ float xs[HIDDEN];
  __shared__ float red[4];
  __shared__ float srstd;
  float ss = 0.f;
  for (int i = threadIdx.x; i < HIDDEN; i += 256) {
    const float v = planes[(size_t)row * HIDDEN + i] + planes[PSTR + (size_t)row * HIDDEN + i];
    xs[i] = v;
    ss += v * v;
  }
#pragma unroll
  for (int off = 32; off >= 1; off >>= 1) ss += __shfl_down(ss, off);
  if ((threadIdx.x & 63) == 0) red[threadIdx.x >> 6] = ss;
  __syncthreads();
  if (threadIdx.x == 0)
    srstd = rsqrtf((red[0] + red[1] + red[2] + red[3]) / (float)HIDDEN + 1e-6f);
  __syncthreads();
  const float rstd1 = srstd;
  float ss2 = 0.f;
  for (int i = threadIdx.x; i < HIDDEN; i += 256) {
    const float h = res[(size_t)row * HIDDEN + i] + xs[i] * rstd1 * (1.f + w1[i]);
    hf[(size_t)row * HIDDEN + i] = h;
    ss2 += h * h;
  }
  __syncthreads();  // xs reads done before overwrite pattern (we overwrite below)
  for (int i = threadIdx.x; i < HIDDEN; i += 256)
    xs[i] = hf[(size_t)row * HIDDEN + i];
  // (re-read from Hf to keep xs consistent; L2-hot)
#pragma unroll
  for (int off = 32; off >= 1; off >>= 1) ss2 += __shfl_down(ss2, off);
  if ((threadIdx.x & 63) == 0) red[threadIdx.x >> 6] = ss2;
  __syncthreads();
  if (threadIdx.x == 0)
    srstd = rsqrtf((red[0] + red[1] + red[2] + red[3]) / (float)HIDDEN + 1e-6f);
  __syncthreads();
  const float rstd2 = srstd;
  for (int i = threadIdx.x; i < HIDDEN; i += 256)
    xb[(size_t)row * HIDDEN + i] = __float2bfloat16(xs[i] * rstd2 * (1.f + w2[i]));
}

// ---------------- bf16 GEMM (m97 structure + XCD swizzle): C = A * Bt^T ----------------
template <int EPI>
__global__ __launch_bounds__(256) void k_gemm_bt(const __hip_bfloat16* __restrict__ A,
                                                 const __hip_bfloat16* __restrict__ Bt,
                                                 void* __restrict__ Cv,
                                                 const __hip_bfloat16* __restrict__ G,
                                                 int N, int K) {
  __shared__ alignas(16) __hip_bfloat16 sA[128 * 64];
  __shared__ alignas(16) __hip_bfloat16 sB[128 * 64];
  const int t = threadIdx.x;
  const int w = t >> 6;
  const int wm = w >> 1, wn = w & 1;
  const int nwg = gridDim.x * gridDim.y;
  const int fblk = blockIdx.y * gridDim.x + blockIdx.x;
  const int qq = nwg >> 3, r8 = nwg & 7;
  const int xcd = fblk & 7, ix = fblk >> 3;
  const int swz = (xcd < r8 ? xcd * (qq + 1) : r8 * (qq + 1) + (xcd - r8) * qq) + ix;
  const int m0 = (swz % gridDim.y) * 128, n0 = (swz / gridDim.y) * 128;
  const int lr = t & 15, lg = (t & 63) >> 4;
  const int srow = t >> 3, sc8 = t & 7;

  f32x4 acc[4][4];
#pragma unroll
  for (int a = 0; a < 4; a++)
#pragma unroll
    for (int b = 0; b < 4; b++) acc[a][b] = (f32x4){0.f, 0.f, 0.f, 0.f};

  for (int kt = 0; kt < K; kt += 64) {
#pragma unroll
    for (int i = 0; i < 4; i++) {
      const __hip_bfloat16* g = A + (size_t)(m0 + i * 32 + srow) * K + kt + sc8 * 8;
      gload_lds16(g, sA + (size_t)(i * 256 + w * 64) * 8);
    }
#pragma unroll
    for (int i = 0; i < 4; i++) {
      const __hip_bfloat16* g = Bt + (size_t)(n0 + i * 32 + srow) * K + kt + sc8 * 8;
      gload_lds16(g, sB + (size_t)(i * 256 + w * 64) * 8);
    }
    __syncthreads();
#pragma unroll
    for (int ks = 0; ks < 2; ks++) {
      s16x8 af[4], bfr[4];
#pragma unroll
      for (int fm = 0; fm < 4; fm++)
        af[fm] = *reinterpret_cast<const s16x8*>(sA + (wm * 64 + fm * 16 + lr) * 64 + ks * 32 + lg * 8);
#pragma unroll
      for (int fn = 0; fn < 4; fn++)
        bfr[fn] = *reinterpret_cast<const s16x8*>(sB + (wn * 64 + fn * 16 + lr) * 64 + ks * 32 + lg * 8);
#pragma unroll
      for (int fm = 0; fm < 4; fm++)
#pragma unroll
        for (int fn = 0; fn < 4; fn++)
          acc[fm][fn] = __builtin_amdgcn_mfma_f32_16x16x32_bf16(af[fm], bfr[fn], acc[fm][fn], 0, 0, 0);
    }
    __syncthreads();
  }
#pragma unroll
  for (int fm = 0; fm < 4; fm++) {
    const int rb = m0 + wm * 64 + fm * 16 + lg * 4;
#pragma unroll
    for (int fn = 0; fn < 4; fn++) {
      const int col = n0 + wn * 64 + fn * 16 + lr;
#pragma unroll
      for (int j = 0; j < 4; j++) {
        const size_t idx = (size_t)(rb + j) * N + col;
        if constexpr (EPI == 0) {
          ((float*)Cv)[idx] = acc[fm][fn][j];
        } else if constexpr (EPI == 1) {
          ((__hip_bfloat16*)Cv)[idx] = __float2bfloat16(acc[fm][fn][j]);
        } else {
          const float x = __bfloat162float(G[idx]);
          const float tt = tanhf(0.7978845608028654f * (x + 0.044715f * x * x * x));
          ((__hip_bfloat16*)Cv)[idx] = __float2bfloat16(0.5f * x * (1.f + tt) * acc[fm][fn][j]);
        }
      }
    }
  }
}

// ---------- 8-phase 256x256 bf16 GEMM (split-K capable) — proven r7 kernel ----------
// EPI: 4 f32 split: plane0 -> Cv, plane1 -> Cv2
template <int EPI>
__global__ __launch_bounds__(512, 2) void k_gemm8(const __hip_bfloat16* __restrict__ A,
                                                  const __hip_bfloat16* __restrict__ Bt,
                                                  void* __restrict__ Cv,
                                                  const __hip_bfloat16* __restrict__ G,
                                                  const __hip_bfloat16* __restrict__ Bt2,
                                                  void* __restrict__ Cv2,
                                                  int N, int K, int keff) {
  __shared__ alignas(16) __hip_bfloat16 smem[65536];  // 128 KiB
  const int t = threadIdx.x;
  const int w = t >> 6;
  const int wm = w >> 2, wn = w & 3;
  const int l = t & 63;
  const int lr = l & 15, lg = l >> 4;

  const int nxy = gridDim.x * gridDim.y;
  const int nwg = nxy * gridDim.z;
  const int fblk = blockIdx.z * nxy + blockIdx.y * gridDim.x + blockIdx.x;
  const int qq = nwg >> 3, r8 = nwg & 7;
  const int xcd = fblk & 7, ix = fblk >> 3;
  const int swz = (xcd < r8 ? xcd * (qq + 1) : r8 * (qq + 1) + (xcd - r8) * qq) + ix;
  const int plane = swz / nxy;
  const int rem = swz % nxy;
  const int m0 = (rem % gridDim.y) * 256, n0 = (rem / gridDim.y) * 256;
  const int k0 = plane * keff;

  const int sA8 = l & 7;
  size_t aoff[2], boff[2];
#pragma unroll
  for (int j = 0; j < 2; j++) {
    const int rv = (w * 2 + j) * 8 + (l >> 3);
    const int ko = (sA8 ^ (rv & 7)) * 8;
    aoff[j] = (size_t)(m0 + ((rv >> 6) & 1) * 128 + ((rv >> 4) & 3) * 16 + (rv & 15)) * K + k0 + ko;
    boff[j] = (size_t)(n0 + ((rv >> 5) & 3) * 64 + ((rv >> 4) & 1) * 16 + (rv & 15)) * K + k0 + ko;
  }
  const int sl0 = ((lg) ^ (lr & 7)) * 8;
  const int sl1 = ((4 + lg) ^ (lr & 7)) * 8;

  f32x4 acc[8][4];
#pragma unroll
  for (int a = 0; a < 8; a++)
#pragma unroll
    for (int b = 0; b < 4; b++) acc[a][b] = (f32x4){0.f, 0.f, 0.f, 0.f};
  s16x8 af[4][2], bf[2][2];

#define STG_A(bu, h, kti) { _Pragma("unroll") for (int j = 0; j < 2; j++) \
    gload_lds16(A + aoff[j] + (size_t)(h) * 64 * K + (size_t)(kti) * 64, \
                smem + (bu) * 32768 + (h) * 8192 + (w * 2 + j) * 512); }
#define STG_B(bu, h, kti) { _Pragma("unroll") for (int j = 0; j < 2; j++) \
    gload_lds16(Bt + boff[j] + (size_t)(h) * 32 * K + (size_t)(kti) * 64, \
                smem + (bu) * 32768 + 16384 + (h) * 8192 + (w * 2 + j) * 512); }
#define RD_A(bu, fmh) { const __hip_bfloat16* ab_ = smem + (bu) * 32768; \
    _Pragma("unroll") for (int f2 = 0; f2 < 4; f2++) { \
      const int ro_ = ((fmh) * 128 + wm * 64 + f2 * 16 + lr) * 64; \
      af[f2][0] = *(const s16x8*)(ab_ + ro_ + sl0); \
      af[f2][1] = *(const s16x8*)(ab_ + ro_ + sl1); } }
#define RD_B(bu, fnh) { const __hip_bfloat16* bb_ = smem + (bu) * 32768 + 16384; \
    _Pragma("unroll") for (int f2 = 0; f2 < 2; f2++) { \
      const int ro_ = ((fnh) * 128 + wn * 32 + f2 * 16 + lr) * 64; \
      bf[f2][0] = *(const s16x8*)(bb_ + ro_ + sl0); \
      bf[f2][1] = *(const s16x8*)(bb_ + ro_ + sl1); } }
#define MFMA16(fmh, fnh) { __builtin_amdgcn_s_setprio(1); \
    _Pragma("unroll") for (int f2 = 0; f2 < 4; f2++) \
    _Pragma("unroll") for (int g2 = 0; g2 < 2; g2++) \
    _Pragma("unroll") for (int ks = 0; ks < 2; ks++) \
      acc[(fmh) * 4 + f2][(fnh) * 2 + g2] = __builtin_amdgcn_mfma_f32_16x16x32_bf16( \
          af[f2][ks], bf[g2][ks], acc[(fmh) * 4 + f2][(fnh) * 2 + g2], 0, 0, 0); \
    __builtin_amdgcn_s_setprio(0); }
#define BARR() asm volatile("s_barrier" ::: "memory")
#define LGKM0() asm volatile("s_waitcnt lgkmcnt(0)" ::: "memory")
#define VMC4() asm volatile("s_waitcnt vmcnt(4)" ::: "memory")
#define VMC0() asm volatile("s_waitcnt vmcnt(0)" ::: "memory")

  STG_A(0, 0, 0); STG_A(0, 1, 0); STG_B(0, 0, 0); STG_B(0, 1, 0);
  STG_A(1, 0, 1); STG_A(1, 1, 1);
  VMC4(); BARR();

  const int niter = keff >> 7;
  for (int i = 0; i < niter; ++i) {
    const int t1 = 2 * i + 1;
    const bool more = (i + 1 < niter);
    RD_A(0, 0); RD_B(0, 0);
    STG_B(1, 0, t1);
    BARR(); LGKM0(); MFMA16(0, 0); BARR();
    RD_B(0, 1);
    STG_B(1, 1, t1);
    if (more) STG_A(0, 0, t1 + 1);
    BARR(); LGKM0(); MFMA16(0, 1); BARR();
    RD_A(0, 1); RD_B(0, 0);
    BARR(); LGKM0(); MFMA16(1, 0); BARR();
    RD_B(0, 1);
    if (more) STG_A(0, 1, t1 + 1);
    BARR(); LGKM0(); MFMA16(1, 1);
    if (more) { VMC4(); } else { VMC0(); }
    BARR();
    RD_A(1, 0); RD_B(1, 0);
    if (more) STG_B(0, 0, t1 + 1);
    BARR(); LGKM0(); MFMA16(0, 0); BARR();
    RD_B(1, 1);
    if (more) STG_B(0, 1, t1 + 1);
    BARR(); LGKM0(); MFMA16(0, 1); BARR();
    RD_A(1, 1); RD_B(1, 0);
    if (more) STG_A(1, 0, t1 + 2);
    BARR(); LGKM0(); MFMA16(1, 0); BARR();
    RD_B(1, 1);
    if (more) STG_A(1, 1, t1 + 2);
    BARR(); LGKM0(); MFMA16(1, 1);
    if (more) { VMC4(); }
    BARR();
  }
#undef STG_A
#undef STG_B
#undef RD_A
#undef RD_B
#undef MFMA16
#undef BARR
#undef LGKM0
#undef VMC4
#undef VMC0

#pragma unroll
  for (int fm = 0; fm < 8; fm++) {
    const int rb = m0 + wm * 128 + fm * 16 + lg * 4;
#pragma unroll
    for (int fn = 0; fn < 4; fn++) {
      const int coln = wn * 64 + fn * 16 + lr;
#pragma unroll
      for (int j = 0; j < 4; j++) {
        const size_t idxo = (size_t)(rb + j) * N + n0 + coln;
        if constexpr (EPI == 4) {
          float* P = (plane == 0) ? (float*)Cv : (float*)Cv2;
          P[idxo] = acc[fm][fn][j];
        } else {
          ((__hip_bfloat16*)Cv)[idxo] = __float2bfloat16(acc[fm][fn][j]);
        }
      }
    }
  }
}

// ---- 4-phase 128x256 bf16 GEMM (finer grid granularity; same swizzle/vmcnt discipline) ----
// 512 thr = 8 waves (2M x 4N); wave tile 64x64 (two 32-col strips); BK=64, 2 K-tiles/iter.
// LDS 96 KiB: 2 bufs x (A 128x64 + B 256x64). B halves = contiguous row ranges (fnh*128).
// Schedule (per iter): ph0{RD A0,B0h0; STG B1h1(t1)} ph1{RD B0h1; STG A0,B0h0(t0'); VMC4}
//                      ph2{RD A1,B1h0; STG B0h1(t0')} ph3{RD B1h1; STG A1,B1h0(t1'); VMC4}
// VMC4 leaves the 4 newest (next-next tile) outstanding; forces the 6 of the next tile landed.
// EPI: 3 DUAL gate+up (n0<FFDIM: Bt/Cv else Bt2/Cv2, stride FFDIM); 5 bf16 split Cv+plane*PSTR.
template <int EPI>
__global__ __launch_bounds__(512, 2) void k_gemm8h(const __hip_bfloat16* __restrict__ A,
                                                   const __hip_bfloat16* __restrict__ Bt,
                                                   void* __restrict__ Cv,
                                                   const __hip_bfloat16* __restrict__ Bt2,
                                                   void* __restrict__ Cv2,
                                                   int N, int K, int keff) {
  __shared__ alignas(16) __hip_bfloat16 smem[49152];  // 96 KiB: buf = A[0,8192) B[8192,24576)
  const int t = threadIdx.x;
  const int w = t >> 6;
  const int wm = w >> 2, wn = w & 3;
  const int l = t & 63;
  const int lr = l & 15, lg = l >> 4;

  const int nxy = gridDim.x * gridDim.y;
  const int nwg = nxy * gridDim.z;
  const int fblk = blockIdx.z * nxy + blockIdx.y * gridDim.x + blockIdx.x;
  const int qq = nwg >> 3, r8 = nwg & 7;
  const int xcd = fblk & 7, ix = fblk >> 3;
  const int swz = (xcd < r8 ? xcd * (qq + 1) : r8 * (qq + 1) + (xcd - r8) * qq) + ix;
  const int plane = swz / nxy;
  const int rem = swz % nxy;
  const int m0 = (rem % gridDim.y) * 128, n0 = (rem / gridDim.y) * 256;
  const int k0 = plane * keff;

  const __hip_bfloat16* Bsrc = Bt;
  int nb0 = n0;
  if constexpr (EPI == 3) {
    if (n0 >= FFDIM) { Bsrc = Bt2; nb0 = n0 - FFDIM; }
  }

  // staging: issue j covers local rows [j*64, j*64+64); thread -> row j*64 + w*8 + (l>>3),
  // k-slot (l&7); inverse-swizzle: global k-block = (l&7) ^ (l>>3)  [row&7 == l>>3].
  const int lrow = w * 8 + (l >> 3);
  const int ko = (((l & 7) ^ (l >> 3))) * 8;
  const size_t aoffh = (size_t)(m0 + lrow) * K + k0 + ko;          // + j*64*K
  const size_t boffh = (size_t)(nb0 + lrow) * K + k0 + ko;         // + j*64*K
  const int sl0 = ((lg) ^ (lr & 7)) * 8;
  const int sl1 = ((4 + lg) ^ (lr & 7)) * 8;

  f32x4 acc[4][4];
#pragma unroll
  for (int a = 0; a < 4; a++)
#pragma unroll
    for (int b = 0; b < 4; b++) acc[a][b] = (f32x4){0.f, 0.f, 0.f, 0.f};
  s16x8 af[4][2], bf[2][2];

#define HSTG_A(bu, kti) { _Pragma("unroll") for (int j = 0; j < 2; j++) \
    gload_lds16(A + aoffh + (size_t)j * 64 * K + (size_t)(kti) * 64, \
                smem + (bu) * 24576 + (j * 64 + w * 8) * 64); }
#define HSTG_B0(bu, kti) { _Pragma("unroll") for (int j = 0; j < 2; j++) \
    gload_lds16(Bsrc + boffh + (size_t)j * 64 * K + (size_t)(kti) * 64, \
                smem + (bu) * 24576 + 8192 + (j * 64 + w * 8) * 64); }
#define HSTG_B1(bu, kti) { _Pragma("unroll") for (int j = 2; j < 4; j++) \
    gload_lds16(Bsrc + boffh + (size_t)j * 64 * K + (size_t)(kti) * 64, \
                smem + (bu) * 24576 + 8192 + (j * 64 + w * 8) * 64); }
#define HRD_A(bu) { const __hip_bfloat16* ab_ = smem + (bu) * 24576; \
    _Pragma("unroll") for (int f2 = 0; f2 < 4; f2++) { \
      const int ro_ = (wm * 64 + f2 * 16 + lr) * 64; \
      af[f2][0] = *(const s16x8*)(ab_ + ro_ + sl0); \
      af[f2][1] = *(const s16x8*)(ab_ + ro_ + sl1); } }
#define HRD_B(bu, fnh) { const __hip_bfloat16* bb_ = smem + (bu) * 24576 + 8192; \
    _Pragma("unroll") for (int f2 = 0; f2 < 2; f2++) { \
      const int ro_ = ((fnh) * 128 + wn * 32 + f2 * 16 + lr) * 64; \
      bf[f2][0] = *(const s16x8*)(bb_ + ro_ + sl0); \
      bf[f2][1] = *(const s16x8*)(bb_ + ro_ + sl1); } }
#define HMFMA16(fnh) { __builtin_amdgcn_s_setprio(1); \
    _Pragma("unroll") for (int f2 = 0; f2 < 4; f2++) \
    _Pragma("unroll") for (int g2 = 0; g2 < 2; g2++) \
    _Pragma("unroll") for (int ks = 0; ks < 2; ks++) \
      acc[f2][(fnh) * 2 + g2] = __builtin_amdgcn_mfma_f32_16x16x32_bf16( \
          af[f2][ks], bf[g2][ks], acc[f2][(fnh) * 2 + g2], 0, 0, 0); \
    __builtin_amdgcn_s_setprio(0); }
#define HBARR() asm volatile("s_barrier" ::: "memory")
#define HLGKM0() asm volatile("s_waitcnt lgkmcnt(0)" ::: "memory")
#define HVMC4() asm volatile("s_waitcnt vmcnt(4)" ::: "memory")
#define HVMC0() asm volatile("s_waitcnt vmcnt(0)" ::: "memory")

  // prologue: t0 full (A2+B4) -> b0; t1 A2+Bh0 -> b1; VMC4 leaves t1's 4 outstanding
  HSTG_A(0, 0); HSTG_B0(0, 0); HSTG_B1(0, 0);
  HSTG_A(1, 1); HSTG_B0(1, 1);
  HVMC4(); HBARR();

  const int niter = keff >> 7;  // 2 tiles/iter (requires keff % 128 == 0)
  for (int i = 0; i < niter; ++i) {
    const int t1 = 2 * i + 1;
    const bool more = (i + 1 < niter);
    // ph0: compute T0/fnh0; finish t1 staging (Bh1)
    HRD_A(0); HRD_B(0, 0);
    HSTG_B1(1, t1);
    HBARR(); HLGKM0(); HMFMA16(0); HBARR();
    // ph1: T0/fnh1; stage t0' A+Bh0 -> b0 (A,Bh0 of b0 lgkm-retired in ph0); wait t1 landed
    HRD_B(0, 1);
    if (more) { HSTG_A(0, t1 + 1); HSTG_B0(0, t1 + 1); }
    HBARR(); HLGKM0(); HMFMA16(1);
    if (more) { HVMC4(); } else { HVMC0(); }
    HBARR();
    // ph2: T1/fnh0; stage t0' Bh1 (b0 Bh1 retired in ph1)
    HRD_A(1); HRD_B(1, 0);
    if (more) HSTG_B1(0, t1 + 1);
    HBARR(); HLGKM0(); HMFMA16(0); HBARR();
    // ph3: T1/fnh1; stage t1' A+Bh0 -> b1 (retired in ph2); wait t0' landed
    HRD_B(1, 1);
    if (more) { HSTG_A(1, t1 + 2); HSTG_B0(1, t1 + 2); }
    HBARR(); HLGKM0(); HMFMA16(1);
    if (more) { HVMC4(); }
    HBARR();
  }
#undef HSTG_A
#undef HSTG_B0
#undef HSTG_B1
#undef HRD_A
#undef HRD_B
#undef HMFMA16
#undef HBARR
#undef HLGKM0
#undef HVMC4
#undef HVMC0

  // epilogue: C/D col = lane&15, row = (lane>>4)*4 + reg; wave cols = two 32-strips
  __hip_bfloat16* Cw;
  int cbase, cstride;
  if constexpr (EPI == 3) {
    Cw = (__hip_bfloat16*)((n0 < FFDIM) ? Cv : Cv2);
    cbase = (n0 < FFDIM) ? n0 : n0 - FFDIM;
    cstride = FFDIM;
  } else {
    Cw = (__hip_bfloat16*)Cv + (size_t)plane * PSTR;
    cbase = n0;
    cstride = N;
  }
#pragma unroll
  for (int fm = 0; fm < 4; fm++) {
    const int rb = m0 + wm * 64 + fm * 16 + lg * 4;
#pragma unroll
    for (int fn = 0; fn < 4; fn++) {
      const int coln = (fn >> 1) * 128 + wn * 32 + (fn & 1) * 16 + lr;
#pragma unroll
      for (int j = 0; j < 4; j++)
        Cw[(size_t)(rb + j) * cstride + cbase + coln] = __float2bfloat16(acc[fm][fn][j]);
    }
  }
}

// ---------------- gelu(g) * u, all bf16, vectorized x8; o may alias g ----------------
__global__ void k_gelu_mul2(const __hip_bfloat16* __restrict__ g, const __hip_bfloat16* __restrict__ u,
                            __hip_bfloat16* __restrict__ o, int n8) {
  const int st = gridDim.x * blockDim.x;
  for (int i = blockIdx.x * blockDim.x + threadIdx.x; i < n8; i += st) {
    s16x8 gv = *(const s16x8*)(g + (size_t)i * 8);
    s16x8 uv = *(const s16x8*)(u + (size_t)i * 8);
    s16x8 ov;
#pragma unroll
    for (int j = 0; j < 8; j++) {
      const float x = __uint_as_float(((uint32_t)(uint16_t)gv[j]) << 16);
      const float uu = __uint_as_float(((uint32_t)(uint16_t)uv[j]) << 16);
      const float tt = tanhf(0.7978845608028654f * (x + 0.044715f * x * x * x));
      const float r = 0.5f * x * (1.f + tt) * uu;
      ov[j] = (short)(__hip_bfloat16_raw(__float2bfloat16(r)).x);
    }
    *(s16x8*)(o + (size_t)i * 8) = ov;
  }
}

// ------ rope + split + scale: qkv = P0 + P1 (two f32 partial planes) -> Q/K bf16 head-major ------
__global__ void k_rope_split(const float* __restrict__ p0, const float* __restrict__ p1,
                             const float* __restrict__ cosb, const float* __restrict__ sinb,
                             __hip_bfloat16* __restrict__ qo, __hip_bfloat16* __restrict__ ko) {
  const int s = blockIdx.x;
  const float* r0 = p0 + (size_t)s * QKVN;
  const float* r1 = p1 + (size_t)s * QKVN;
  const float* cr = cosb + (size_t)s * 128;
  const float* sr = sinb + (size_t)s * 128;
  for (int idx = threadIdx.x; idx < (NHEAD + NKVH) * 128; idx += 256) {
    const int hh = idx >> 7, d = idx & 127;
    const float cv = cr[d], sv = sr[d];
    if (hh < NHEAD) {
      const float x1 = r0[hh * DHEAD + d] + r1[hh * DHEAD + d];
      const float x2 = r0[hh * DHEAD + 128 + d] + r1[hh * DHEAD + 128 + d];
      const size_t base = ((size_t)hh * S_LEN + s) * DHEAD;
      qo[base + d]       = __float2bfloat16((x1 * cv - x2 * sv) * QSCALE);
      qo[base + 128 + d] = __float2bfloat16((x1 * sv + x2 * cv) * QSCALE);
    } else {
      const int kv = hh - NHEAD;
      const int o1 = NHEAD * DHEAD + kv * DHEAD + d;
      const float x1 = r0[o1] + r1[o1];
      const float x2 = r0[o1 + 128] + r1[o1 + 128];
      const size_t base = ((size_t)kv * S_LEN + s) * DHEAD;
      ko[base + d]       = __float2bfloat16(x1 * cv - x2 * sv);
      ko[base + 128 + d] = __float2bfloat16(x1 * sv + x2 * cv);
    }
  }
}

// -------- V extract + transpose from 2 partial planes: -> Vt[kv][256 d][2048 s] bf16 --------
__global__ __launch_bounds__(256) void k_vsplit_t(const float* __restrict__ p0,
                                                  const float* __restrict__ p1,
                                                  __hip_bfloat16* __restrict__ vt) {
  __shared__ float tile[64][260];
  const int s0 = blockIdx.x * 64, kv = blockIdx.y;
  const int t = threadIdx.x;
  const int rr = t >> 6, c4 = t & 63;
#pragma unroll
  for (int p = 0; p < 16; p++) {
    const int row = rr + p * 4;
    const size_t go = (size_t)(s0 + row) * QKVN + (NHEAD + NKVH) * DHEAD + kv * DHEAD + c4 * 4;
    const float4 v0 = *(const float4*)(p0 + go);
    const float4 v1 = *(const float4*)(p1 + go);
    float4 v;
    v.x = v0.x + v1.x; v.y = v0.y + v1.y; v.z = v0.z + v1.z; v.w = v0.w + v1.w;
    *(float4*)(&tile[row][c4 * 4]) = v;
  }
  __syncthreads();
  const int c = t & 31, dr = t >> 5;
#pragma unroll
  for (int p = 0; p < 32; p++) {
    const int d = dr + p * 8;
    __hip_bfloat162 pr;
    pr.x = __float2bfloat16(tile[2 * c][d]);
    pr.y = __float2bfloat16(tile[2 * c + 1][d]);
    *(__hip_bfloat162*)(vt + ((size_t)kv * DHEAD + d) * S_LEN + s0 + 2 * c) = pr;
  }
}

// ---------------- MFMA flash attention: sliding-window causal + softcap ----------------
__global__ __launch_bounds__(256) void k_attn_mfma(const __hip_bfloat16* __restrict__ Q,
                                                   const __hip_bfloat16* __restrict__ Kb,
                                                   const __hip_bfloat16* __restrict__ Vt,
                                                   __hip_bfloat16* __restrict__ O) {
  __shared__ alignas(16) __hip_bfloat16 Ks[64 * 264];
  __shared__ alignas(16) __hip_bfloat16 Vs[256 * 72];
  __shared__ alignas(16) __hip_bfloat16 Ps[64 * 72];
  const int h = blockIdx.y, kvh = h >> 1;
  const int q0 = blockIdx.x * 64;
  const int t = threadIdx.x;
  const int wq = t >> 6;
  const int l = t & 63;
  const int lr = l & 15, lg = l >> 4;

  s16x8 qf[8];
  {
    const __hip_bfloat16* qrow = Q + ((size_t)h * S_LEN + q0 + wq * 16 + lr) * DHEAD;
#pragma unroll
    for (int ks = 0; ks < 8; ks++) qf[ks] = *(const s16x8*)(qrow + ks * 32 + lg * 8);
  }
  f32x4 acc[16];
#pragma unroll
  for (int i = 0; i < 16; i++) acc[i] = (f32x4){0.f, 0.f, 0.f, 0.f};
  float rsum[4] = {0.f, 0.f, 0.f, 0.f};

  int lo = q0 - WINM1;
  if (lo < 0) lo = 0;
  lo &= ~63;
  const int qrow_base = q0 + wq * 16 + lg * 4;

  for (int kc = lo; kc <= q0; kc += 64) {
#pragma unroll
    for (int p = 0; p < 8; p++) {
      const int idx = t + p * 256;
      const int row = idx >> 5, c16 = idx & 31;
      s16x8 v = *(const s16x8*)(Kb + ((size_t)kvh * S_LEN + kc + row) * DHEAD + c16 * 8);
      *(s16x8*)(Ks + row * 264 + c16 * 8) = v;
    }
#pragma unroll
    for (int p = 0; p < 8; p++) {
      const int idx = t + p * 256;
      const int d = idx >> 3, ch = idx & 7;
      s16x8 v = *(const s16x8*)(Vt + ((size_t)kvh * DHEAD + d) * S_LEN + kc + ch * 8);
      *(s16x8*)(Vs + d * 72 + ch * 8) = v;
    }
    __syncthreads();

    f32x4 sc[4];
#pragma unroll
    for (int fq = 0; fq < 4; fq++) {
      sc[fq] = (f32x4){0.f, 0.f, 0.f, 0.f};
#pragma unroll
      for (int ks = 0; ks < 8; ks++) {
        s16x8 bfr = *(const s16x8*)(Ks + (fq * 16 + lr) * 264 + ks * 32 + lg * 8);
        sc[fq] = __builtin_amdgcn_mfma_f32_16x16x32_bf16(qf[ks], bfr, sc[fq], 0, 0, 0);
      }
    }
#pragma unroll
    for (int fq = 0; fq < 4; fq++) {
      const int k = kc + fq * 16 + lr;
#pragma unroll
      for (int j = 0; j < 4; j++) {
        const int qw = qrow_base + j;
        float p = 0.f;
        if (k <= qw && qw - k <= WINM1) {
          const float s = sc[fq][j];
          const float u = exp2f(s * 0.057707801635558534f);
          const float arg = 72.134752044448169f -
                            144.26950408889634f * __builtin_amdgcn_rcpf(u + 1.f);
          p = exp2f(arg);
        }
        const __hip_bfloat16 pb = __float2bfloat16(p);
        Ps[(wq * 16 + lg * 4 + j) * 72 + fq * 16 + lr] = pb;
        rsum[j] += __bfloat162float(pb);
      }
    }
#pragma unroll
    for (int ks2 = 0; ks2 < 2; ks2++) {
      s16x8 pa = *(const s16x8*)(Ps + (wq * 16 + lr) * 72 + ks2 * 32 + lg * 8);
#pragma unroll
      for (int f2 = 0; f2 < 16; f2++) {
        s16x8 vb = *(const s16x8*)(Vs + (f2 * 16 + lr) * 72 + ks2 * 32 + lg * 8);
        acc[f2] = __builtin_amdgcn_mfma_f32_16x16x32_bf16(pa, vb, acc[f2], 0, 0, 0);
      }
    }
    __syncthreads();
  }
#pragma unroll
  for (int j = 0; j < 4; j++) {
    float s = rsum[j];
#pragma unroll
    for (int off = 1; off < 16; off <<= 1) s += __shfl_xor(s, off, 64);
    rsum[j] = 1.f / s;
  }
#pragma unroll
  for (int f2 = 0; f2 < 16; f2++)
#pragma unroll
    for (int j = 0; j < 4; j++)
      O[(size_t)(qrow_base + j) * ODIM + h * DHEAD + f2 * 16 + lr] =
          __float2bfloat16(acc[f2][j] * rsum[j]);
}

// ---------------- launcher ----------------
extern "C" void kernel_launch(void* const* d_in, const int* in_sizes, int n_in,
                              void* d_out, int out_size, void* d_ws, size_t ws_size,
                              hipStream_t stream) {
  const float* hidden  = (const float*)d_in[0];
  const float* qkv_w   = (const float*)d_in[1];
  const float* o_w     = (const float*)d_in[2];
  const float* gate_w  = (const float*)d_in[3];
  const float* up_w    = (const float*)d_in[4];
  const float* down_w  = (const float*)d_in[5];
  const float* in_ln   = (const float*)d_in[6];
  const float* post_attn_ln = (const float*)d_in[7];
  const float* pre_ffw_ln   = (const float*)d_in[8];
  const float* post_ffw_ln  = (const float*)d_in[9];
  const float* cosb    = (const float*)d_in[10];
  const float* sinb    = (const float*)d_in[11];
  float* out = (float*)d_out;
  char* ws = (char*)d_ws;

  // ---- workspace layout (bytes) ----
  const size_t OFF_W   = 0;          // 42.47 MB reusable transposed-weight slot
  const size_t OFF_HF  = 42467328;   // h residual f32
  const size_t OFF_X   = 61341696;   // x_norm bf16
  const size_t OFF_S1  = 70778880;   // 37.75 MB
  const size_t OFF_S2  = 108527616;  // 37.75 MB
  const size_t NEED    = 146276352;
  const size_t OFF_W2  = 146276352;  // 42.47 MB (up^T; qkv partial plane1; down partial tail)
  const size_t NEED_F  = 188743680;

  if (ws_size < NEED) {
    k_fill<<<1024, 256, 0, stream>>>(out, 100000.0f + (float)(ws_size >> 20), (size_t)out_size);
    return;
  }
  const bool FUSED = (ws_size >= NEED_F);

  __hip_bfloat16* W    = (__hip_bfloat16*)(ws + OFF_W);
  __hip_bfloat16* W2   = (__hip_bfloat16*)(ws + OFF_W2);
  float*          Hf   = (float*)(ws + OFF_HF);
  __hip_bfloat16* Xb   = (__hip_bfloat16*)(ws + OFF_X);
  __hip_bfloat16* GATEB= (__hip_bfloat16*)(ws + OFF_S1);
  __hip_bfloat16* UPB  = (__hip_bfloat16*)(ws + OFF_S2);
  __hip_bfloat16* Qb   = (__hip_bfloat16*)(ws + OFF_S2);
  __hip_bfloat16* Kb   = (__hip_bfloat16*)(ws + OFF_S2 + 8388608);
  __hip_bfloat16* Vtb  = (__hip_bfloat16*)(ws + OFF_S2 + 12582912);
  __hip_bfloat16* ATTN = (__hip_bfloat16*)(ws + OFF_S2 + 29360128);

  if (FUSED) {
    float* QKV0 = (float*)(ws + OFF_S1);
    float* QKV1 = (float*)(ws + OFF_W2);
    float* PROJ = (float*)(ws + OFF_S1);
    __hip_bfloat16* DPART = (__hip_bfloat16*)(ws + OFF_S2);  // 8 bf16 planes (75.5 MB)

    // 1. qkv^T -> W ; x = rmsnorm(hidden) -> Xb ; qkv = Xb @ W^T (256^2 8-phase, split-K=2)
    k_transpose_bf16<<<dim3(QKVN / 32, HIDDEN / 32), 256, 0, stream>>>(qkv_w, W, HIDDEN, QKVN);
    k_rmsnorm<1, false, false, true><<<S_LEN, 256, 0, stream>>>(hidden, in_ln, nullptr, Xb);
    k_gemm8<4><<<dim3(QKVN / 256, S_LEN / 256, 2), 512, 0, stream>>>(
        Xb, W, QKV0, nullptr, nullptr, QKV1, QKVN, HIDDEN, HIDDEN / 2);
    // 2. rope+split Q/K ; V extract+transpose
    k_rope_split<<<S_LEN, 256, 0, stream>>>(QKV0, QKV1, cosb, sinb, Qb, Kb);
    k_vsplit_t<<<dim3(S_LEN / 64, NKVH), 256, 0, stream>>>(QKV0, QKV1, Vtb);
    // 3. attention -> ATTN (bf16)
    k_attn_mfma<<<dim3(S_LEN / 64, NHEAD), 256, 0, stream>>>(Qb, Kb, Vtb, ATTN);
    // 4. o^T -> W ; proj = ATTN @ W^T (256^2 8-phase, split-K=2)
    k_transpose_bf16<<<dim3(HIDDEN / 32, ODIM / 32), 256, 0, stream>>>(o_w, W, ODIM, HIDDEN);
    k_gemm8<4><<<dim3(HIDDEN / 256, S_LEN / 256, 2), 512, 0, stream>>>(
        ATTN, W, PROJ, nullptr, nullptr, PROJ + PSTR, HIDDEN, ODIM, ODIM / 2);
    // 5. fused: h = hidden + rmsnorm(proj) -> Hf ; x2 = rmsnorm(h) -> Xb
    k_rmsnorm2<<<S_LEN, 256, 0, stream>>>(PROJ, post_attn_ln, hidden, pre_ffw_ln, Hf, Xb);
    // 6. gate^T -> W, up^T -> W2; fused gate+up GEMM (128x256 blocks, 1152)
    k_transpose_bf16<<<dim3(FFDIM / 32, HIDDEN / 32), 256, 0, stream>>>(gate_w, W, HIDDEN, FFDIM);
    k_transpose_bf16<<<dim3(FFDIM / 32, HIDDEN / 32), 256, 0, stream>>>(up_w, W2, HIDDEN, FFDIM);
    k_gemm8h<3><<<dim3((2 * FFDIM) / 256, S_LEN / 128, 1), 512, 0, stream>>>(
        Xb, W, GATEB, W2, UPB, FFDIM, HIDDEN, HIDDEN);
    // 7. act = gelu(gate)*up, in-place over S1
    k_gelu_mul2<<<2048, 256, 0, stream>>>(GATEB, UPB, GATEB, (S_LEN * FFDIM) / 8);
    // 8. down^T -> W ; y-partials = ACT @ W^T (128x256 blocks, split-K=8, bf16 planes)
    k_transpose_bf16<<<dim3(HIDDEN / 32, FFDIM / 32), 256, 0, stream>>>(down_w, W, FFDIM, HIDDEN);
    k_gemm8h<5><<<dim3(HIDDEN / 256, S_LEN / 128, 8), 512, 0, stream>>>(
        GATEB, W, DPART, nullptr, nullptr, HIDDEN, FFDIM, FFDIM / 8);
    // 9. out = h + rmsnorm(sum of 8 partials)
    k_rmsnorm<8, true, true, false><<<S_LEN, 256, 0, stream>>>(DPART, post_ffw_ln, Hf, out);
  } else {
    // fallback: round-5-style path (no split-K, zero plane1 via Hf)
    float* QKV = (float*)(ws + OFF_S1);
    float* PROJ = (float*)(ws + OFF_S2);
    k_transpose_bf16<<<dim3(QKVN / 32, HIDDEN / 32), 256, 0, stream>>>(qkv_w, W, HIDDEN, QKVN);
    k_rmsnorm<1, false, false, true><<<S_LEN, 256, 0, stream>>>(hidden, in_ln, nullptr, Xb);
    k_gemm_bt<0><<<dim3(QKVN / 128, S_LEN / 128), 256, 0, stream>>>(Xb, W, QKV, nullptr, QKVN, HIDDEN);
    k_fill<<<1024, 256, 0, stream>>>(Hf, 0.f, PSTR);
    k_rope_split<<<S_LEN, 256, 0, stream>>>(QKV, Hf, cosb, sinb, Qb, Kb);
    k_vsplit_t<<<dim3(S_LEN / 64, NKVH), 256, 0, stream>>>(QKV, Hf, Vtb);
    k_attn_mfma<<<dim3(S_LEN / 64, NHEAD), 256, 0, stream>>>(Qb, Kb, Vtb, ATTN);
    k_transpose_bf16<<<dim3(HIDDEN / 32, ODIM / 32), 256, 0, stream>>>(o_w, W, ODIM, HIDDEN);
    k_gemm_bt<0><<<dim3(HIDDEN / 128, S_LEN / 128), 256, 0, stream>>>(ATTN, W, PROJ, nullptr, HIDDEN, ODIM);
    k_rmsnorm<1, false, true, false><<<S_LEN, 256, 0, stream>>>(PROJ, post_attn_ln, hidden, Hf);
    k_rmsnorm<1, false, false, true><<<S_LEN, 256, 0, stream>>>(Hf, pre_ffw_ln, nullptr, Xb);
    k_transpose_bf16<<<dim3(FFDIM / 32, HIDDEN / 32), 256, 0, stream>>>(gate_w, W, HIDDEN, FFDIM);
    k_gemm_bt<1><<<dim3(FFDIM / 128, S_LEN / 128), 256, 0, stream>>>(Xb, W, GATEB, nullptr, FFDIM, HIDDEN);
    __hip_bfloat16* ACT = (__hip_bfloat16*)(ws + OFF_S2);
    k_transpose_bf16<<<dim3(FFDIM / 32, HIDDEN / 32), 256, 0, stream>>>(up_w, W, HIDDEN, FFDIM);
    k_gemm_bt<2><<<dim3(FFDIM / 128, S_LEN / 128), 256, 0, stream>>>(Xb, W, ACT, GATEB, FFDIM, HIDDEN);
    float* Yf = (float*)(ws + OFF_S1);
    k_transpose_bf16<<<dim3(HIDDEN / 32, FFDIM / 32), 256, 0, stream>>>(down_w, W, FFDIM, HIDDEN);
    k_gemm_bt<0><<<dim3(HIDDEN / 128, S_LEN / 128), 256, 0, stream>>>(ACT, W, Yf, nullptr, HIDDEN, FFDIM);
    k_rmsnorm<1, false, true, false><<<S_LEN, 256, 0, stream>>>(Yf, post_ffw_ln, Hf, out);
  }
}

// Round 9
// 682.898 us; speedup vs baseline: 1.0325x; 1.0325x over previous
//
#include <hip/hip_runtime.h>
#include <hip/hip_bf16.h>
#include <cstdint>
#include <cstddef>

// ---------------- constants ----------------
#define S_LEN  2048
#define HIDDEN 2304
#define NHEAD  8
#define NKVH   4
#define DHEAD  256
#define FFDIM  9216
#define QKVN   4096   // (H + 2*KV) * D
#define ODIM   2048   // H * D
#define WINM1  1023
#define QSCALE 0.0625f
#define CAPF   50.0f
#define PSTR   ((size_t)S_LEN * HIDDEN)   // partial-plane stride (elements)

typedef __attribute__((ext_vector_type(4))) float f32x4;
typedef __attribute__((ext_vector_type(8))) short s16x8;

// async global->LDS 16B copy; lptr must be wave-uniform, HW adds lane*16
__device__ __forceinline__ void gload_lds16(const void* gptr, void* lptr) {
  __builtin_amdgcn_global_load_lds(
      (const __attribute__((address_space(1))) unsigned int*)gptr,
      (__attribute__((address_space(3))) unsigned int*)lptr, 16, 0, 0);
}

// ---------------- diagnostic fill (ws too small): value encodes ws MiB ----------------
__global__ void k_fill(float* p, float v, size_t n) {
  size_t i = (size_t)blockIdx.x * blockDim.x + threadIdx.x;
  size_t st = (size_t)gridDim.x * blockDim.x;
  for (; i < n; i += st) p[i] = v;
}

// ---------------- f32 [R][C] -> bf16 [C][R] ----------------
__global__ void k_transpose_bf16(const float* __restrict__ in, __hip_bfloat16* __restrict__ out,
                                 int R, int C) {
  __shared__ float tile[32][33];
  const int c0 = blockIdx.x * 32, r0 = blockIdx.y * 32;
  const int tc = threadIdx.x & 31, tr = threadIdx.x >> 5;  // 32 x 8
#pragma unroll
  for (int i = 0; i < 4; i++)
    tile[tr + 8 * i][tc] = in[(size_t)(r0 + tr + 8 * i) * C + c0 + tc];
  __syncthreads();
#pragma unroll
  for (int i = 0; i < 4; i++)
    out[(size_t)(c0 + tr + 8 * i) * R + r0 + tc] = __float2bfloat16(tile[tc][tr + 8 * i]);
}

// ------ rmsnorm over sum of NP planes (plane stride PSTR); optional residual; f32/bf16 out ------
template <int NP, bool INBF16, bool ADD, bool BF16OUT>
__global__ void k_rmsnorm(const void* __restrict__ xv, const float* __restrict__ w,
                          const float* __restrict__ res, void* __restrict__ outv) {
  const int row = blockIdx.x;
  __shared__ float xs[HIDDEN];
  float ss = 0.f;
  for (int i = threadIdx.x; i < HIDDEN; i += 256) {
    float v = 0.f;
#pragma unroll
    for (int p = 0; p < NP; p++) {
      if constexpr (INBF16)
        v += __bfloat162float(((const __hip_bfloat16*)xv)[(size_t)p * PSTR + (size_t)row * HIDDEN + i]);
      else
        v += ((const float*)xv)[(size_t)p * PSTR + (size_t)row * HIDDEN + i];
    }
    xs[i] = v;
    ss += v * v;
  }
#pragma unroll
  for (int off = 32; off >= 1; off >>= 1) ss += __shfl_down(ss, off);
  __shared__ float red[4];
  __shared__ float srstd;
  if ((threadIdx.x & 63) == 0) red[threadIdx.x >> 6] = ss;
  __syncthreads();
  if (threadIdx.x == 0) {
    float tot = red[0] + red[1] + red[2] + red[3];
    srstd = rsqrtf(tot / (float)HIDDEN + 1e-6f);
  }
  __syncthreads();
  const float rstd = srstd;
  for (int i = threadIdx.x; i < HIDDEN; i += 256) {
    float v = xs[i] * rstd * (1.f + w[i]);
    if constexpr (ADD) v += res[(size_t)row * HIDDEN + i];
    if constexpr (BF16OUT)
      ((__hip_bfloat16*)outv)[(size_t)row * HIDDEN + i] = __float2bfloat16(v);
    else
      ((float*)outv)[(size_t)row * HIDDEN + i] = v;
  }
}

// ---- fused: h = res + rmsnorm(P0+P1)*(1+w1) -> Hf(f32); x2 = rmsnorm(h)*(1+w2) -> Xb(bf16) ----
__global__ void k_rmsnorm2(const float* __restrict__ planes, const float* __restrict__ w1,
                           const float* __restrict__ res, const float* __restrict__ w2,
                           float* __restrict__ hf, __hip_bfloat16* __restrict__ xb) {
  const int row = blockIdx.x;
  __shared__ float xs[HIDDEN];
  __shared__ float red[4];
  __shared__ float srstd;
  float ss = 0.f;
  for (int i = threadIdx.x; i < HIDDEN; i += 256) {
    const float v = planes[(size_t)row * HIDDEN + i] + planes[PSTR + (size_t)row * HIDDEN + i];
    xs[i] = v;
    ss += v * v;
  }
#pragma unroll
  for (int off = 32; off >= 1; off >>= 1) ss += __shfl_down(ss, off);
  if ((threadIdx.x & 63) == 0) red[threadIdx.x >> 6] = ss;
  __syncthreads();
  if (threadIdx.x == 0)
    srstd = rsqrtf((red[0] + red[1] + red[2] + red[3]) / (float)HIDDEN + 1e-6f);
  __syncthreads();
  const float rstd1 = srstd;
  float ss2 = 0.f;
  for (int i = threadIdx.x; i < HIDDEN; i += 256) {
    const float h = res[(size_t)row * HIDDEN + i] + xs[i] * rstd1 * (1.f + w1[i]);
    hf[(size_t)row * HIDDEN + i] = h;
    ss2 += h * h;
  }
  __syncthreads();
  for (int i = threadIdx.x; i < HIDDEN; i += 256)
    xs[i] = hf[(size_t)row * HIDDEN + i];
#pragma unroll
  for (int off = 32; off >= 1; off >>= 1) ss2 += __shfl_down(ss2, off);
  if ((threadIdx.x & 63) == 0) red[threadIdx.x >> 6] = ss2;
  __syncthreads();
  if (threadIdx.x == 0)
    srstd = rsqrtf((red[0] + red[1] + red[2] + red[3]) / (float)HIDDEN + 1e-6f);
  __syncthreads();
  const float rstd2 = srstd;
  for (int i = threadIdx.x; i < HIDDEN; i += 256)
    xb[(size_t)row * HIDDEN + i] = __float2bfloat16(xs[i] * rstd2 * (1.f + w2[i]));
}

// ---------------- bf16 GEMM (m97 structure + XCD swizzle): C = A * Bt^T ----------------
template <int EPI>
__global__ __launch_bounds__(256) void k_gemm_bt(const __hip_bfloat16* __restrict__ A,
                                                 const __hip_bfloat16* __restrict__ Bt,
                                                 void* __restrict__ Cv,
                                                 const __hip_bfloat16* __restrict__ G,
                                                 int N, int K) {
  __shared__ alignas(16) __hip_bfloat16 sA[128 * 64];
  __shared__ alignas(16) __hip_bfloat16 sB[128 * 64];
  const int t = threadIdx.x;
  const int w = t >> 6;
  const int wm = w >> 1, wn = w & 1;
  const int nwg = gridDim.x * gridDim.y;
  const int fblk = blockIdx.y * gridDim.x + blockIdx.x;
  const int qq = nwg >> 3, r8 = nwg & 7;
  const int xcd = fblk & 7, ix = fblk >> 3;
  const int swz = (xcd < r8 ? xcd * (qq + 1) : r8 * (qq + 1) + (xcd - r8) * qq) + ix;
  const int m0 = (swz % gridDim.y) * 128, n0 = (swz / gridDim.y) * 128;
  const int lr = t & 15, lg = (t & 63) >> 4;
  const int srow = t >> 3, sc8 = t & 7;

  f32x4 acc[4][4];
#pragma unroll
  for (int a = 0; a < 4; a++)
#pragma unroll
    for (int b = 0; b < 4; b++) acc[a][b] = (f32x4){0.f, 0.f, 0.f, 0.f};

  for (int kt = 0; kt < K; kt += 64) {
#pragma unroll
    for (int i = 0; i < 4; i++) {
      const __hip_bfloat16* g = A + (size_t)(m0 + i * 32 + srow) * K + kt + sc8 * 8;
      gload_lds16(g, sA + (size_t)(i * 256 + w * 64) * 8);
    }
#pragma unroll
    for (int i = 0; i < 4; i++) {
      const __hip_bfloat16* g = Bt + (size_t)(n0 + i * 32 + srow) * K + kt + sc8 * 8;
      gload_lds16(g, sB + (size_t)(i * 256 + w * 64) * 8);
    }
    __syncthreads();
#pragma unroll
    for (int ks = 0; ks < 2; ks++) {
      s16x8 af[4], bfr[4];
#pragma unroll
      for (int fm = 0; fm < 4; fm++)
        af[fm] = *reinterpret_cast<const s16x8*>(sA + (wm * 64 + fm * 16 + lr) * 64 + ks * 32 + lg * 8);
#pragma unroll
      for (int fn = 0; fn < 4; fn++)
        bfr[fn] = *reinterpret_cast<const s16x8*>(sB + (wn * 64 + fn * 16 + lr) * 64 + ks * 32 + lg * 8);
#pragma unroll
      for (int fm = 0; fm < 4; fm++)
#pragma unroll
        for (int fn = 0; fn < 4; fn++)
          acc[fm][fn] = __builtin_amdgcn_mfma_f32_16x16x32_bf16(af[fm], bfr[fn], acc[fm][fn], 0, 0, 0);
    }
    __syncthreads();
  }
#pragma unroll
  for (int fm = 0; fm < 4; fm++) {
    const int rb = m0 + wm * 64 + fm * 16 + lg * 4;
#pragma unroll
    for (int fn = 0; fn < 4; fn++) {
      const int col = n0 + wn * 64 + fn * 16 + lr;
#pragma unroll
      for (int j = 0; j < 4; j++) {
        const size_t idx = (size_t)(rb + j) * N + col;
        if constexpr (EPI == 0) {
          ((float*)Cv)[idx] = acc[fm][fn][j];
        } else if constexpr (EPI == 1) {
          ((__hip_bfloat16*)Cv)[idx] = __float2bfloat16(acc[fm][fn][j]);
        } else {
          const float x = __bfloat162float(G[idx]);
          const float tt = tanhf(0.7978845608028654f * (x + 0.044715f * x * x * x));
          ((__hip_bfloat16*)Cv)[idx] = __float2bfloat16(0.5f * x * (1.f + tt) * acc[fm][fn][j]);
        }
      }
    }
  }
}

// ---------- 8-phase 256x256 bf16 GEMM (T2 swizzle + T3/T4 counted vmcnt + T5 setprio) ----------
// B-frag retention (r9): B-halves read ONCE per tile (ph0/ph1, ph4/ph5), retained in regs for
// ph2/ph3, ph6/ph7 -> 48 ds_read_b128/iter (was 64). Staging issue order and vmcnt counts are
// byte-identical to the r7-proven schedule (reads only move earlier -> lifetimes still safe).
// EPI: 0 f32; 1 bf16; 2 bf16 gelu(G)*acc; 3 DUAL gate+up (Bt/Cv | Bt2/Cv2, C stride FFDIM);
//      4 f32 split: plane0 -> Cv, plane1 -> Cv2;  5 bf16 split: Cv + plane*PSTR.
template <int EPI>
__global__ __launch_bounds__(512, 2) void k_gemm8(const __hip_bfloat16* __restrict__ A,
                                                  const __hip_bfloat16* __restrict__ Bt,
                                                  void* __restrict__ Cv,
                                                  const __hip_bfloat16* __restrict__ G,
                                                  const __hip_bfloat16* __restrict__ Bt2,
                                                  void* __restrict__ Cv2,
                                                  int N, int K, int keff) {
  __shared__ alignas(16) __hip_bfloat16 smem[65536];  // 128 KiB
  const int t = threadIdx.x;
  const int w = t >> 6;
  const int wm = w >> 2, wn = w & 3;
  const int l = t & 63;
  const int lr = l & 15, lg = l >> 4;

  const int nxy = gridDim.x * gridDim.y;
  const int nwg = nxy * gridDim.z;
  const int fblk = blockIdx.z * nxy + blockIdx.y * gridDim.x + blockIdx.x;
  const int qq = nwg >> 3, r8 = nwg & 7;
  const int xcd = fblk & 7, ix = fblk >> 3;
  const int swz = (xcd < r8 ? xcd * (qq + 1) : r8 * (qq + 1) + (xcd - r8) * qq) + ix;
  const int plane = swz / nxy;
  const int rem = swz % nxy;
  const int m0 = (rem % gridDim.y) * 256, n0 = (rem / gridDim.y) * 256;
  const int k0 = plane * keff;

  // dual-B selection (EPI 3): block's 256 cols lie entirely in one half (FFDIM % 256 == 0)
  const __hip_bfloat16* Bsrc = Bt;
  int nb0 = n0;
  if constexpr (EPI == 3) {
    if (n0 >= FFDIM) { Bsrc = Bt2; nb0 = n0 - FFDIM; }
  }

  const int sA8 = l & 7;
  size_t aoff[2], boff[2];
#pragma unroll
  for (int j = 0; j < 2; j++) {
    const int rv = (w * 2 + j) * 8 + (l >> 3);
    const int ko = (sA8 ^ (rv & 7)) * 8;  // inverse-swizzled k-slot
    aoff[j] = (size_t)(m0 + ((rv >> 6) & 1) * 128 + ((rv >> 4) & 3) * 16 + (rv & 15)) * K + k0 + ko;
    boff[j] = (size_t)(nb0 + ((rv >> 5) & 3) * 64 + ((rv >> 4) & 1) * 16 + (rv & 15)) * K + k0 + ko;
  }
  const int sl0 = ((lg) ^ (lr & 7)) * 8;       // read slot, ks=0
  const int sl1 = ((4 + lg) ^ (lr & 7)) * 8;   // read slot, ks=1

  f32x4 acc[8][4];
#pragma unroll
  for (int a = 0; a < 8; a++)
#pragma unroll
    for (int b = 0; b < 4; b++) acc[a][b] = (f32x4){0.f, 0.f, 0.f, 0.f};
  s16x8 af[4][2], bfr[2][2][2];  // bfr[fnh][frag][ks] — retained across phases

#define STG_A(bu, h, kti) { _Pragma("unroll") for (int j = 0; j < 2; j++) \
    gload_lds16(A + aoff[j] + (size_t)(h) * 64 * K + (size_t)(kti) * 64, \
                smem + (bu) * 32768 + (h) * 8192 + (w * 2 + j) * 512); }
#define STG_B(bu, h, kti) { _Pragma("unroll") for (int j = 0; j < 2; j++) \
    gload_lds16(Bsrc + boff[j] + (size_t)(h) * 32 * K + (size_t)(kti) * 64, \
                smem + (bu) * 32768 + 16384 + (h) * 8192 + (w * 2 + j) * 512); }
#define RD_A(bu, fmh) { const __hip_bfloat16* ab_ = smem + (bu) * 32768; \
    _Pragma("unroll") for (int f2 = 0; f2 < 4; f2++) { \
      const int ro_ = ((fmh) * 128 + wm * 64 + f2 * 16 + lr) * 64; \
      af[f2][0] = *(const s16x8*)(ab_ + ro_ + sl0); \
      af[f2][1] = *(const s16x8*)(ab_ + ro_ + sl1); } }
#define RD_BH(bu, fnh) { const __hip_bfloat16* bb_ = smem + (bu) * 32768 + 16384; \
    _Pragma("unroll") for (int f2 = 0; f2 < 2; f2++) { \
      const int ro_ = ((fnh) * 128 + wn * 32 + f2 * 16 + lr) * 64; \
      bfr[fnh][f2][0] = *(const s16x8*)(bb_ + ro_ + sl0); \
      bfr[fnh][f2][1] = *(const s16x8*)(bb_ + ro_ + sl1); } }
#define MFMA16(fmh, fnh) { __builtin_amdgcn_s_setprio(1); \
    _Pragma("unroll") for (int f2 = 0; f2 < 4; f2++) \
    _Pragma("unroll") for (int g2 = 0; g2 < 2; g2++) \
    _Pragma("unroll") for (int ks = 0; ks < 2; ks++) \
      acc[(fmh) * 4 + f2][(fnh) * 2 + g2] = __builtin_amdgcn_mfma_f32_16x16x32_bf16( \
          af[f2][ks], bfr[fnh][g2][ks], acc[(fmh) * 4 + f2][(fnh) * 2 + g2], 0, 0, 0); \
    __builtin_amdgcn_s_setprio(0); }
#define BARR() asm volatile("s_barrier" ::: "memory")
#define LGKM0() asm volatile("s_waitcnt lgkmcnt(0)" ::: "memory")
#define VMC4() asm volatile("s_waitcnt vmcnt(4)" ::: "memory")
#define VMC0() asm volatile("s_waitcnt vmcnt(0)" ::: "memory")

  // prologue: tile0 full (8 loads) + tile1 A-halves (4 loads); vmcnt(4) forces tile0 landed
  STG_A(0, 0, 0); STG_A(0, 1, 0); STG_B(0, 0, 0); STG_B(0, 1, 0);
  STG_A(1, 0, 1); STG_A(1, 1, 1);
  VMC4(); BARR();

  const int niter = keff >> 7;  // keff/128, 2 tiles/iter (requires keff % 128 == 0)
  for (int i = 0; i < niter; ++i) {
    const int t1 = 2 * i + 1;
    const bool more = (i + 1 < niter);
    // ph0: T0 q(fm0,fn0); stage B0(t1)
    RD_A(0, 0); RD_BH(0, 0);
    STG_B(1, 0, t1);
    BARR(); LGKM0(); MFMA16(0, 0); BARR();
    // ph1: q(fm0,fn1); read B-h1 once; stage B1(t1), A0(t0')
    RD_BH(0, 1);
    STG_B(1, 1, t1);
    if (more) STG_A(0, 0, t1 + 1);
    BARR(); LGKM0(); MFMA16(0, 1); BARR();
    // ph2: q(fm1,fn0) — B retained
    RD_A(0, 1);
    BARR(); LGKM0(); MFMA16(1, 0); BARR();
    // ph3: q(fm1,fn1) — all retained; stage A1(t0'); counted wait: tile t1 landed for ph4
    if (more) STG_A(0, 1, t1 + 1);
    BARR(); LGKM0(); MFMA16(1, 1);
    if (more) { VMC4(); } else { VMC0(); }
    BARR();
    // ph4: T1 q(fm0,fn0); stage B0(t0')
    RD_A(1, 0); RD_BH(1, 0);
    if (more) STG_B(0, 0, t1 + 1);
    BARR(); LGKM0(); MFMA16(0, 0); BARR();
    // ph5: q(fm0,fn1); stage B1(t0')
    RD_BH(1, 1);
    if (more) STG_B(0, 1, t1 + 1);
    BARR(); LGKM0(); MFMA16(0, 1); BARR();
    // ph6: q(fm1,fn0); stage A0(t1')
    RD_A(1, 1);
    if (more) STG_A(1, 0, t1 + 2);
    BARR(); LGKM0(); MFMA16(1, 0); BARR();
    // ph7: q(fm1,fn1); stage A1(t1'); counted wait: tile t0' landed for next ph0
    if (more) STG_A(1, 1, t1 + 2);
    BARR(); LGKM0(); MFMA16(1, 1);
    if (more) { VMC4(); }
    BARR();
  }
#undef STG_A
#undef STG_B
#undef RD_A
#undef RD_BH
#undef MFMA16
#undef BARR
#undef LGKM0
#undef VMC4
#undef VMC0

  // epilogue: C/D layout col = lane&15, row = (lane>>4)*4 + reg
  __hip_bfloat16* Cw = nullptr;
  int cbase = n0, cstride = N;
  if constexpr (EPI == 3) {
    Cw = (__hip_bfloat16*)((n0 < FFDIM) ? Cv : Cv2);
    cbase = (n0 < FFDIM) ? n0 : n0 - FFDIM;
    cstride = FFDIM;
  }
#pragma unroll
  for (int fm = 0; fm < 8; fm++) {
    const int rb = m0 + wm * 128 + fm * 16 + lg * 4;
#pragma unroll
    for (int fn = 0; fn < 4; fn++) {
      const int coln = wn * 64 + fn * 16 + lr;
#pragma unroll
      for (int j = 0; j < 4; j++) {
        if constexpr (EPI == 3) {
          Cw[(size_t)(rb + j) * cstride + cbase + coln] = __float2bfloat16(acc[fm][fn][j]);
        } else {
          const size_t idxo = (size_t)(rb + j) * N + n0 + coln;
          if constexpr (EPI == 0) {
            ((float*)Cv)[idxo] = acc[fm][fn][j];
          } else if constexpr (EPI == 1) {
            ((__hip_bfloat16*)Cv)[idxo] = __float2bfloat16(acc[fm][fn][j]);
          } else if constexpr (EPI == 2) {
            const float x = __bfloat162float(G[idxo]);
            const float tg = tanhf(0.7978845608028654f * (x + 0.044715f * x * x * x));
            ((__hip_bfloat16*)Cv)[idxo] = __float2bfloat16(0.5f * x * (1.f + tg) * acc[fm][fn][j]);
          } else if constexpr (EPI == 4) {
            float* P = (plane == 0) ? (float*)Cv : (float*)Cv2;
            P[idxo] = acc[fm][fn][j];
          } else {  // EPI == 5
            ((__hip_bfloat16*)Cv)[(size_t)plane * PSTR + idxo] = __float2bfloat16(acc[fm][fn][j]);
          }
        }
      }
    }
  }
}

// ---------------- gelu(g) * u, all bf16, vectorized x8; o may alias g ----------------
__global__ void k_gelu_mul2(const __hip_bfloat16* __restrict__ g, const __hip_bfloat16* __restrict__ u,
                            __hip_bfloat16* __restrict__ o, int n8) {
  const int st = gridDim.x * blockDim.x;
  for (int i = blockIdx.x * blockDim.x + threadIdx.x; i < n8; i += st) {
    s16x8 gv = *(const s16x8*)(g + (size_t)i * 8);
    s16x8 uv = *(const s16x8*)(u + (size_t)i * 8);
    s16x8 ov;
#pragma unroll
    for (int j = 0; j < 8; j++) {
      const float x = __uint_as_float(((uint32_t)(uint16_t)gv[j]) << 16);
      const float uu = __uint_as_float(((uint32_t)(uint16_t)uv[j]) << 16);
      const float tt = tanhf(0.7978845608028654f * (x + 0.044715f * x * x * x));
      const float r = 0.5f * x * (1.f + tt) * uu;
      ov[j] = (short)(__hip_bfloat16_raw(__float2bfloat16(r)).x);
    }
    *(s16x8*)(o + (size_t)i * 8) = ov;
  }
}

// ------ rope + split + scale: qkv = P0 + P1 (two f32 partial planes) -> Q/K bf16 head-major ------
__global__ void k_rope_split(const float* __restrict__ p0, const float* __restrict__ p1,
                             const float* __restrict__ cosb, const float* __restrict__ sinb,
                             __hip_bfloat16* __restrict__ qo, __hip_bfloat16* __restrict__ ko) {
  const int s = blockIdx.x;
  const float* r0 = p0 + (size_t)s * QKVN;
  const float* r1 = p1 + (size_t)s * QKVN;
  const float* cr = cosb + (size_t)s * 128;
  const float* sr = sinb + (size_t)s * 128;
  for (int idx = threadIdx.x; idx < (NHEAD + NKVH) * 128; idx += 256) {
    const int hh = idx >> 7, d = idx & 127;
    const float cv = cr[d], sv = sr[d];
    if (hh < NHEAD) {
      const float x1 = r0[hh * DHEAD + d] + r1[hh * DHEAD + d];
      const float x2 = r0[hh * DHEAD + 128 + d] + r1[hh * DHEAD + 128 + d];
      const size_t base = ((size_t)hh * S_LEN + s) * DHEAD;
      qo[base + d]       = __float2bfloat16((x1 * cv - x2 * sv) * QSCALE);
      qo[base + 128 + d] = __float2bfloat16((x1 * sv + x2 * cv) * QSCALE);
    } else {
      const int kv = hh - NHEAD;
      const int o1 = NHEAD * DHEAD + kv * DHEAD + d;
      const float x1 = r0[o1] + r1[o1];
      const float x2 = r0[o1 + 128] + r1[o1 + 128];
      const size_t base = ((size_t)kv * S_LEN + s) * DHEAD;
      ko[base + d]       = __float2bfloat16(x1 * cv - x2 * sv);
      ko[base + 128 + d] = __float2bfloat16(x1 * sv + x2 * cv);
    }
  }
}

// -------- V extract + transpose from 2 partial planes: -> Vt[kv][256 d][2048 s] bf16 --------
__global__ __launch_bounds__(256) void k_vsplit_t(const float* __restrict__ p0,
                                                  const float* __restrict__ p1,
                                                  __hip_bfloat16* __restrict__ vt) {
  __shared__ float tile[64][260];
  const int s0 = blockIdx.x * 64, kv = blockIdx.y;
  const int t = threadIdx.x;
  const int rr = t >> 6, c4 = t & 63;
#pragma unroll
  for (int p = 0; p < 16; p++) {
    const int row = rr + p * 4;
    const size_t go = (size_t)(s0 + row) * QKVN + (NHEAD + NKVH) * DHEAD + kv * DHEAD + c4 * 4;
    const float4 v0 = *(const float4*)(p0 + go);
    const float4 v1 = *(const float4*)(p1 + go);
    float4 v;
    v.x = v0.x + v1.x; v.y = v0.y + v1.y; v.z = v0.z + v1.z; v.w = v0.w + v1.w;
    *(float4*)(&tile[row][c4 * 4]) = v;
  }
  __syncthreads();
  const int c = t & 31, dr = t >> 5;
#pragma unroll
  for (int p = 0; p < 32; p++) {
    const int d = dr + p * 8;
    __hip_bfloat162 pr;
    pr.x = __float2bfloat16(tile[2 * c][d]);
    pr.y = __float2bfloat16(tile[2 * c + 1][d]);
    *(__hip_bfloat162*)(vt + ((size_t)kv * DHEAD + d) * S_LEN + s0 + 2 * c) = pr;
  }
}

// ---------------- MFMA flash attention: sliding-window causal + softcap ----------------
__global__ __launch_bounds__(256) void k_attn_mfma(const __hip_bfloat16* __restrict__ Q,
                                                   const __hip_bfloat16* __restrict__ Kb,
                                                   const __hip_bfloat16* __restrict__ Vt,
                                                   __hip_bfloat16* __restrict__ O) {
  __shared__ alignas(16) __hip_bfloat16 Ks[64 * 264];
  __shared__ alignas(16) __hip_bfloat16 Vs[256 * 72];
  __shared__ alignas(16) __hip_bfloat16 Ps[64 * 72];
  const int h = blockIdx.y, kvh = h >> 1;
  const int q0 = blockIdx.x * 64;
  const int t = threadIdx.x;
  const int wq = t >> 6;
  const int l = t & 63;
  const int lr = l & 15, lg = l >> 4;

  s16x8 qf[8];
  {
    const __hip_bfloat16* qrow = Q + ((size_t)h * S_LEN + q0 + wq * 16 + lr) * DHEAD;
#pragma unroll
    for (int ks = 0; ks < 8; ks++) qf[ks] = *(const s16x8*)(qrow + ks * 32 + lg * 8);
  }
  f32x4 acc[16];
#pragma unroll
  for (int i = 0; i < 16; i++) acc[i] = (f32x4){0.f, 0.f, 0.f, 0.f};
  float rsum[4] = {0.f, 0.f, 0.f, 0.f};

  int lo = q0 - WINM1;
  if (lo < 0) lo = 0;
  lo &= ~63;
  const int qrow_base = q0 + wq * 16 + lg * 4;

  for (int kc = lo; kc <= q0; kc += 64) {
#pragma unroll
    for (int p = 0; p < 8; p++) {
      const int idx = t + p * 256;
      const int row = idx >> 5, c16 = idx & 31;
      s16x8 v = *(const s16x8*)(Kb + ((size_t)kvh * S_LEN + kc + row) * DHEAD + c16 * 8);
      *(s16x8*)(Ks + row * 264 + c16 * 8) = v;
    }
#pragma unroll
    for (int p = 0; p < 8; p++) {
      const int idx = t + p * 256;
      const int d = idx >> 3, ch = idx & 7;
      s16x8 v = *(const s16x8*)(Vt + ((size_t)kvh * DHEAD + d) * S_LEN + kc + ch * 8);
      *(s16x8*)(Vs + d * 72 + ch * 8) = v;
    }
    __syncthreads();

    f32x4 sc[4];
#pragma unroll
    for (int fq = 0; fq < 4; fq++) {
      sc[fq] = (f32x4){0.f, 0.f, 0.f, 0.f};
#pragma unroll
      for (int ks = 0; ks < 8; ks++) {
        s16x8 bfr = *(const s16x8*)(Ks + (fq * 16 + lr) * 264 + ks * 32 + lg * 8);
        sc[fq] = __builtin_amdgcn_mfma_f32_16x16x32_bf16(qf[ks], bfr, sc[fq], 0, 0, 0);
      }
    }
#pragma unroll
    for (int fq = 0; fq < 4; fq++) {
      const int k = kc + fq * 16 + lr;
#pragma unroll
      for (int j = 0; j < 4; j++) {
        const int qw = qrow_base + j;
        float p = 0.f;
        if (k <= qw && qw - k <= WINM1) {
          const float s = sc[fq][j];
          const float u = exp2f(s * 0.057707801635558534f);
          const float arg = 72.134752044448169f -
                            144.26950408889634f * __builtin_amdgcn_rcpf(u + 1.f);
          p = exp2f(arg);
        }
        const __hip_bfloat16 pb = __float2bfloat16(p);
        Ps[(wq * 16 + lg * 4 + j) * 72 + fq * 16 + lr] = pb;
        rsum[j] += __bfloat162float(pb);
      }
    }
#pragma unroll
    for (int ks2 = 0; ks2 < 2; ks2++) {
      s16x8 pa = *(const s16x8*)(Ps + (wq * 16 + lr) * 72 + ks2 * 32 + lg * 8);
#pragma unroll
      for (int f2 = 0; f2 < 16; f2++) {
        s16x8 vb = *(const s16x8*)(Vs + (f2 * 16 + lr) * 72 + ks2 * 32 + lg * 8);
        acc[f2] = __builtin_amdgcn_mfma_f32_16x16x32_bf16(pa, vb, acc[f2], 0, 0, 0);
      }
    }
    __syncthreads();
  }
#pragma unroll
  for (int j = 0; j < 4; j++) {
    float s = rsum[j];
#pragma unroll
    for (int off = 1; off < 16; off <<= 1) s += __shfl_xor(s, off, 64);
    rsum[j] = 1.f / s;
  }
#pragma unroll
  for (int f2 = 0; f2 < 16; f2++)
#pragma unroll
    for (int j = 0; j < 4; j++)
      O[(size_t)(qrow_base + j) * ODIM + h * DHEAD + f2 * 16 + lr] =
          __float2bfloat16(acc[f2][j] * rsum[j]);
}

// ---------------- launcher ----------------
extern "C" void kernel_launch(void* const* d_in, const int* in_sizes, int n_in,
                              void* d_out, int out_size, void* d_ws, size_t ws_size,
                              hipStream_t stream) {
  const float* hidden  = (const float*)d_in[0];
  const float* qkv_w   = (const float*)d_in[1];
  const float* o_w     = (const float*)d_in[2];
  const float* gate_w  = (const float*)d_in[3];
  const float* up_w    = (const float*)d_in[4];
  const float* down_w  = (const float*)d_in[5];
  const float* in_ln   = (const float*)d_in[6];
  const float* post_attn_ln = (const float*)d_in[7];
  const float* pre_ffw_ln   = (const float*)d_in[8];
  const float* post_ffw_ln  = (const float*)d_in[9];
  const float* cosb    = (const float*)d_in[10];
  const float* sinb    = (const float*)d_in[11];
  float* out = (float*)d_out;
  char* ws = (char*)d_ws;

  // ---- workspace layout (bytes) ----
  const size_t OFF_W   = 0;          // 42.47 MB reusable transposed-weight slot
  const size_t OFF_HF  = 42467328;   // h residual f32
  const size_t OFF_X   = 61341696;   // x_norm bf16
  const size_t OFF_S1  = 70778880;   // 37.75 MB
  const size_t OFF_S2  = 108527616;  // 37.75 MB
  const size_t NEED    = 146276352;
  const size_t OFF_W2  = 146276352;  // 42.47 MB (up^T; qkv partial plane1; down partial tail)
  const size_t NEED_F  = 188743680;

  if (ws_size < NEED) {
    k_fill<<<1024, 256, 0, stream>>>(out, 100000.0f + (float)(ws_size >> 20), (size_t)out_size);
    return;
  }
  const bool FUSED = (ws_size >= NEED_F);

  __hip_bfloat16* W    = (__hip_bfloat16*)(ws + OFF_W);
  __hip_bfloat16* W2   = (__hip_bfloat16*)(ws + OFF_W2);
  float*          Hf   = (float*)(ws + OFF_HF);
  __hip_bfloat16* Xb   = (__hip_bfloat16*)(ws + OFF_X);
  __hip_bfloat16* GATEB= (__hip_bfloat16*)(ws + OFF_S1);
  __hip_bfloat16* UPB  = (__hip_bfloat16*)(ws + OFF_S2);
  __hip_bfloat16* Qb   = (__hip_bfloat16*)(ws + OFF_S2);
  __hip_bfloat16* Kb   = (__hip_bfloat16*)(ws + OFF_S2 + 8388608);
  __hip_bfloat16* Vtb  = (__hip_bfloat16*)(ws + OFF_S2 + 12582912);
  __hip_bfloat16* ATTN = (__hip_bfloat16*)(ws + OFF_S2 + 29360128);

  if (FUSED) {
    float* QKV0 = (float*)(ws + OFF_S1);
    float* QKV1 = (float*)(ws + OFF_W2);
    float* PROJ = (float*)(ws + OFF_S1);
    __hip_bfloat16* DPART = (__hip_bfloat16*)(ws + OFF_S2);  // 8 bf16 planes (75.5 MB)

    // 1. qkv^T -> W ; x = rmsnorm(hidden) -> Xb ; qkv = Xb @ W^T (256^2 8-phase, split-K=2)
    k_transpose_bf16<<<dim3(QKVN / 32, HIDDEN / 32), 256, 0, stream>>>(qkv_w, W, HIDDEN, QKVN);
    k_rmsnorm<1, false, false, true><<<S_LEN, 256, 0, stream>>>(hidden, in_ln, nullptr, Xb);
    k_gemm8<4><<<dim3(QKVN / 256, S_LEN / 256, 2), 512, 0, stream>>>(
        Xb, W, QKV0, nullptr, nullptr, QKV1, QKVN, HIDDEN, HIDDEN / 2);
    // 2. rope+split Q/K ; V extract+transpose
    k_rope_split<<<S_LEN, 256, 0, stream>>>(QKV0, QKV1, cosb, sinb, Qb, Kb);
    k_vsplit_t<<<dim3(S_LEN / 64, NKVH), 256, 0, stream>>>(QKV0, QKV1, Vtb);
    // 3. attention -> ATTN (bf16)
    k_attn_mfma<<<dim3(S_LEN / 64, NHEAD), 256, 0, stream>>>(Qb, Kb, Vtb, ATTN);
    // 4. o^T -> W ; proj = ATTN @ W^T (256^2 8-phase, split-K=2)
    k_transpose_bf16<<<dim3(HIDDEN / 32, ODIM / 32), 256, 0, stream>>>(o_w, W, ODIM, HIDDEN);
    k_gemm8<4><<<dim3(HIDDEN / 256, S_LEN / 256, 2), 512, 0, stream>>>(
        ATTN, W, PROJ, nullptr, nullptr, PROJ + PSTR, HIDDEN, ODIM, ODIM / 2);
    // 5. fused: h = hidden + rmsnorm(proj) -> Hf ; x2 = rmsnorm(h) -> Xb
    k_rmsnorm2<<<S_LEN, 256, 0, stream>>>(PROJ, post_attn_ln, hidden, pre_ffw_ln, Hf, Xb);
    // 6. gate^T -> W, up^T -> W2; ONE 576-block fused GEMM -> GATEB(S1) + UPB(S2)
    k_transpose_bf16<<<dim3(FFDIM / 32, HIDDEN / 32), 256, 0, stream>>>(gate_w, W, HIDDEN, FFDIM);
    k_transpose_bf16<<<dim3(FFDIM / 32, HIDDEN / 32), 256, 0, stream>>>(up_w, W2, HIDDEN, FFDIM);
    k_gemm8<3><<<dim3((2 * FFDIM) / 256, S_LEN / 256, 1), 512, 0, stream>>>(
        Xb, W, GATEB, nullptr, W2, UPB, FFDIM, HIDDEN, HIDDEN);
    // 7. act = gelu(gate)*up, in-place over S1
    k_gelu_mul2<<<2048, 256, 0, stream>>>(GATEB, UPB, GATEB, (S_LEN * FFDIM) / 8);
    // 8. down^T -> W ; y-partials = ACT @ W^T (256^2 8-phase, split-K=8, bf16 planes)
    k_transpose_bf16<<<dim3(HIDDEN / 32, FFDIM / 32), 256, 0, stream>>>(down_w, W, FFDIM, HIDDEN);
    k_gemm8<5><<<dim3(HIDDEN / 256, S_LEN / 256, 8), 512, 0, stream>>>(
        GATEB, W, DPART, nullptr, nullptr, nullptr, HIDDEN, FFDIM, FFDIM / 8);
    // 9. out = h + rmsnorm(sum of 8 partials)
    k_rmsnorm<8, true, true, false><<<S_LEN, 256, 0, stream>>>(DPART, post_ffw_ln, Hf, out);
  } else {
    // fallback: no split-K (zero plane1 via Hf)
    float* QKV = (float*)(ws + OFF_S1);
    float* PROJ = (float*)(ws + OFF_S2);
    k_transpose_bf16<<<dim3(QKVN / 32, HIDDEN / 32), 256, 0, stream>>>(qkv_w, W, HIDDEN, QKVN);
    k_rmsnorm<1, false, false, true><<<S_LEN, 256, 0, stream>>>(hidden, in_ln, nullptr, Xb);
    k_gemm_bt<0><<<dim3(QKVN / 128, S_LEN / 128), 256, 0, stream>>>(Xb, W, QKV, nullptr, QKVN, HIDDEN);
    k_fill<<<1024, 256, 0, stream>>>(Hf, 0.f, PSTR);
    k_rope_split<<<S_LEN, 256, 0, stream>>>(QKV, Hf, cosb, sinb, Qb, Kb);
    k_vsplit_t<<<dim3(S_LEN / 64, NKVH), 256, 0, stream>>>(QKV, Hf, Vtb);
    k_attn_mfma<<<dim3(S_LEN / 64, NHEAD), 256, 0, stream>>>(Qb, Kb, Vtb, ATTN);
    k_transpose_bf16<<<dim3(HIDDEN / 32, ODIM / 32), 256, 0, stream>>>(o_w, W, ODIM, HIDDEN);
    k_gemm_bt<0><<<dim3(HIDDEN / 128, S_LEN / 128), 256, 0, stream>>>(ATTN, W, PROJ, nullptr, HIDDEN, ODIM);
    k_rmsnorm<1, false, true, false><<<S_LEN, 256, 0, stream>>>(PROJ, post_attn_ln, hidden, Hf);
    k_rmsnorm<1, false, false, true><<<S_LEN, 256, 0, stream>>>(Hf, pre_ffw_ln, nullptr, Xb);
    k_transpose_bf16<<<dim3(FFDIM / 32, HIDDEN / 32), 256, 0, stream>>>(gate_w, W, HIDDEN, FFDIM);
    k_gemm_bt<1><<<dim3(FFDIM / 128, S_LEN / 128), 256, 0, stream>>>(Xb, W, GATEB, nullptr, FFDIM, HIDDEN);
    __hip_bfloat16* ACT = (__hip_bfloat16*)(ws + OFF_S2);
    k_transpose_bf16<<<dim3(FFDIM / 32, HIDDEN / 32), 256, 0, stream>>>(up_w, W, HIDDEN, FFDIM);
    k_gemm_bt<2><<<dim3(FFDIM / 128, S_LEN / 128), 256, 0, stream>>>(Xb, W, ACT, GATEB, FFDIM, HIDDEN);
    float* Yf = (float*)(ws + OFF_S1);
    k_transpose_bf16<<<dim3(HIDDEN / 32, FFDIM / 32), 256, 0, stream>>>(down_w, W, FFDIM, HIDDEN);
    k_gemm_bt<0><<<dim3(HIDDEN / 128, S_LEN / 128), 256, 0, stream>>>(ACT, W, Yf, nullptr, HIDDEN, FFDIM);
    k_rmsnorm<1, false, true, false><<<S_LEN, 256, 0, stream>>>(Yf, post_ffw_ln, Hf, out);
  }
}

// Round 10
// 647.710 us; speedup vs baseline: 1.0886x; 1.0543x over previous
//
#include <hip/hip_runtime.h>
#include <hip/hip_bf16.h>
#include <cstdint>
#include <cstddef>

// ---------------- constants ----------------
#define S_LEN  2048
#define HIDDEN 2304
#define NHEAD  8
#define NKVH   4
#define DHEAD  256
#define FFDIM  9216
#define QKVN   4096   // (H + 2*KV) * D
#define ODIM   2048   // H * D
#define WINM1  1023
#define QSCALE 0.0625f
#define CAPF   50.0f
#define PSTR   ((size_t)S_LEN * HIDDEN)   // partial-plane stride (elements)

typedef __attribute__((ext_vector_type(4))) float f32x4;
typedef __attribute__((ext_vector_type(8))) short s16x8;

// async global->LDS 16B copy; lptr must be wave-uniform, HW adds lane*16
__device__ __forceinline__ void gload_lds16(const void* gptr, void* lptr) {
  __builtin_amdgcn_global_load_lds(
      (const __attribute__((address_space(1))) unsigned int*)gptr,
      (__attribute__((address_space(3))) unsigned int*)lptr, 16, 0, 0);
}

// ---------------- diagnostic fill (ws too small): value encodes ws MiB ----------------
__global__ void k_fill(float* p, float v, size_t n) {
  size_t i = (size_t)blockIdx.x * blockDim.x + threadIdx.x;
  size_t st = (size_t)gridDim.x * blockDim.x;
  for (; i < n; i += st) p[i] = v;
}

// ---------------- f32 [R][C] -> bf16 [C][R] ----------------
__global__ void k_transpose_bf16(const float* __restrict__ in, __hip_bfloat16* __restrict__ out,
                                 int R, int C) {
  __shared__ float tile[32][33];
  const int c0 = blockIdx.x * 32, r0 = blockIdx.y * 32;
  const int tc = threadIdx.x & 31, tr = threadIdx.x >> 5;  // 32 x 8
#pragma unroll
  for (int i = 0; i < 4; i++)
    tile[tr + 8 * i][tc] = in[(size_t)(r0 + tr + 8 * i) * C + c0 + tc];
  __syncthreads();
#pragma unroll
  for (int i = 0; i < 4; i++)
    out[(size_t)(c0 + tr + 8 * i) * R + r0 + tc] = __float2bfloat16(tile[tc][tr + 8 * i]);
}

// ------ rmsnorm over sum of NP planes (plane stride PSTR); optional residual; f32/bf16 out ------
template <int NP, bool INBF16, bool ADD, bool BF16OUT>
__global__ void k_rmsnorm(const void* __restrict__ xv, const float* __restrict__ w,
                          const float* __restrict__ res, void* __restrict__ outv) {
  const int row = blockIdx.x;
  __shared__ float xs[HIDDEN];
  float ss = 0.f;
  for (int i = threadIdx.x; i < HIDDEN; i += 256) {
    float v = 0.f;
#pragma unroll
    for (int p = 0; p < NP; p++) {
      if constexpr (INBF16)
        v += __bfloat162float(((const __hip_bfloat16*)xv)[(size_t)p * PSTR + (size_t)row * HIDDEN + i]);
      else
        v += ((const float*)xv)[(size_t)p * PSTR + (size_t)row * HIDDEN + i];
    }
    xs[i] = v;
    ss += v * v;
  }
#pragma unroll
  for (int off = 32; off >= 1; off >>= 1) ss += __shfl_down(ss, off);
  __shared__ float red[4];
  __shared__ float srstd;
  if ((threadIdx.x & 63) == 0) red[threadIdx.x >> 6] = ss;
  __syncthreads();
  if (threadIdx.x == 0) {
    float tot = red[0] + red[1] + red[2] + red[3];
    srstd = rsqrtf(tot / (float)HIDDEN + 1e-6f);
  }
  __syncthreads();
  const float rstd = srstd;
  for (int i = threadIdx.x; i < HIDDEN; i += 256) {
    float v = xs[i] * rstd * (1.f + w[i]);
    if constexpr (ADD) v += res[(size_t)row * HIDDEN + i];
    if constexpr (BF16OUT)
      ((__hip_bfloat16*)outv)[(size_t)row * HIDDEN + i] = __float2bfloat16(v);
    else
      ((float*)outv)[(size_t)row * HIDDEN + i] = v;
  }
}

// ---- fused: h = res + rmsnorm(P0+P1)*(1+w1) -> Hf(f32); x2 = rmsnorm(h)*(1+w2) -> Xb(bf16) ----
__global__ void k_rmsnorm2(const float* __restrict__ planes, const float* __restrict__ w1,
                           const float* __restrict__ res, const float* __restrict__ w2,
                           float* __restrict__ hf, __hip_bfloat16* __restrict__ xb) {
  const int row = blockIdx.x;
  __shared__ float xs[HIDDEN];
  __shared__ float red[4];
  __shared__ float srstd;
  float ss = 0.f;
  for (int i = threadIdx.x; i < HIDDEN; i += 256) {
    const float v = planes[(size_t)row * HIDDEN + i] + planes[PSTR + (size_t)row * HIDDEN + i];
    xs[i] = v;
    ss += v * v;
  }
#pragma unroll
  for (int off = 32; off >= 1; off >>= 1) ss += __shfl_down(ss, off);
  if ((threadIdx.x & 63) == 0) red[threadIdx.x >> 6] = ss;
  __syncthreads();
  if (threadIdx.x == 0)
    srstd = rsqrtf((red[0] + red[1] + red[2] + red[3]) / (float)HIDDEN + 1e-6f);
  __syncthreads();
  const float rstd1 = srstd;
  float ss2 = 0.f;
  for (int i = threadIdx.x; i < HIDDEN; i += 256) {
    const float h = res[(size_t)row * HIDDEN + i] + xs[i] * rstd1 * (1.f + w1[i]);
    hf[(size_t)row * HIDDEN + i] = h;
    ss2 += h * h;
  }
  __syncthreads();
  for (int i = threadIdx.x; i < HIDDEN; i += 256)
    xs[i] = hf[(size_t)row * HIDDEN + i];
#pragma unroll
  for (int off = 32; off >= 1; off >>= 1) ss2 += __shfl_down(ss2, off);
  if ((threadIdx.x & 63) == 0) red[threadIdx.x >> 6] = ss2;
  __syncthreads();
  if (threadIdx.x == 0)
    srstd = rsqrtf((red[0] + red[1] + red[2] + red[3]) / (float)HIDDEN + 1e-6f);
  __syncthreads();
  const float rstd2 = srstd;
  for (int i = threadIdx.x; i < HIDDEN; i += 256)
    xb[(size_t)row * HIDDEN + i] = __float2bfloat16(xs[i] * rstd2 * (1.f + w2[i]));
}

// ---------------- bf16 GEMM (m97 structure + XCD swizzle): C = A * Bt^T ----------------
template <int EPI>
__global__ __launch_bounds__(256) void k_gemm_bt(const __hip_bfloat16* __restrict__ A,
                                                 const __hip_bfloat16* __restrict__ Bt,
                                                 void* __restrict__ Cv,
                                                 const __hip_bfloat16* __restrict__ G,
                                                 int N, int K) {
  __shared__ alignas(16) __hip_bfloat16 sA[128 * 64];
  __shared__ alignas(16) __hip_bfloat16 sB[128 * 64];
  const int t = threadIdx.x;
  const int w = t >> 6;
  const int wm = w >> 1, wn = w & 1;
  const int nwg = gridDim.x * gridDim.y;
  const int fblk = blockIdx.y * gridDim.x + blockIdx.x;
  const int qq = nwg >> 3, r8 = nwg & 7;
  const int xcd = fblk & 7, ix = fblk >> 3;
  const int swz = (xcd < r8 ? xcd * (qq + 1) : r8 * (qq + 1) + (xcd - r8) * qq) + ix;
  const int m0 = (swz % gridDim.y) * 128, n0 = (swz / gridDim.y) * 128;
  const int lr = t & 15, lg = (t & 63) >> 4;
  const int srow = t >> 3, sc8 = t & 7;

  f32x4 acc[4][4];
#pragma unroll
  for (int a = 0; a < 4; a++)
#pragma unroll
    for (int b = 0; b < 4; b++) acc[a][b] = (f32x4){0.f, 0.f, 0.f, 0.f};

  for (int kt = 0; kt < K; kt += 64) {
#pragma unroll
    for (int i = 0; i < 4; i++) {
      const __hip_bfloat16* g = A + (size_t)(m0 + i * 32 + srow) * K + kt + sc8 * 8;
      gload_lds16(g, sA + (size_t)(i * 256 + w * 64) * 8);
    }
#pragma unroll
    for (int i = 0; i < 4; i++) {
      const __hip_bfloat16* g = Bt + (size_t)(n0 + i * 32 + srow) * K + kt + sc8 * 8;
      gload_lds16(g, sB + (size_t)(i * 256 + w * 64) * 8);
    }
    __syncthreads();
#pragma unroll
    for (int ks = 0; ks < 2; ks++) {
      s16x8 af[4], bfr[4];
#pragma unroll
      for (int fm = 0; fm < 4; fm++)
        af[fm] = *reinterpret_cast<const s16x8*>(sA + (wm * 64 + fm * 16 + lr) * 64 + ks * 32 + lg * 8);
#pragma unroll
      for (int fn = 0; fn < 4; fn++)
        bfr[fn] = *reinterpret_cast<const s16x8*>(sB + (wn * 64 + fn * 16 + lr) * 64 + ks * 32 + lg * 8);
#pragma unroll
      for (int fm = 0; fm < 4; fm++)
#pragma unroll
        for (int fn = 0; fn < 4; fn++)
          acc[fm][fn] = __builtin_amdgcn_mfma_f32_16x16x32_bf16(af[fm], bfr[fn], acc[fm][fn], 0, 0, 0);
    }
    __syncthreads();
  }
#pragma unroll
  for (int fm = 0; fm < 4; fm++) {
    const int rb = m0 + wm * 64 + fm * 16 + lg * 4;
#pragma unroll
    for (int fn = 0; fn < 4; fn++) {
      const int col = n0 + wn * 64 + fn * 16 + lr;
#pragma unroll
      for (int j = 0; j < 4; j++) {
        const size_t idx = (size_t)(rb + j) * N + col;
        if constexpr (EPI == 0) {
          ((float*)Cv)[idx] = acc[fm][fn][j];
        } else if constexpr (EPI == 1) {
          ((__hip_bfloat16*)Cv)[idx] = __float2bfloat16(acc[fm][fn][j]);
        } else {
          const float x = __bfloat162float(G[idx]);
          const float tt = tanhf(0.7978845608028654f * (x + 0.044715f * x * x * x));
          ((__hip_bfloat16*)Cv)[idx] = __float2bfloat16(0.5f * x * (1.f + tt) * acc[fm][fn][j]);
        }
      }
    }
  }
}

// ---------- 8-phase 256x256 bf16 GEMM (r9-proven, B-retention) — used for qkv ----------
// EPI: 4 f32 split: plane0 -> Cv, plane1 -> Cv2
template <int EPI>
__global__ __launch_bounds__(512, 2) void k_gemm8(const __hip_bfloat16* __restrict__ A,
                                                  const __hip_bfloat16* __restrict__ Bt,
                                                  void* __restrict__ Cv,
                                                  const __hip_bfloat16* __restrict__ G,
                                                  const __hip_bfloat16* __restrict__ Bt2,
                                                  void* __restrict__ Cv2,
                                                  int N, int K, int keff) {
  __shared__ alignas(16) __hip_bfloat16 smem[65536];  // 128 KiB
  const int t = threadIdx.x;
  const int w = t >> 6;
  const int wm = w >> 2, wn = w & 3;
  const int l = t & 63;
  const int lr = l & 15, lg = l >> 4;

  const int nxy = gridDim.x * gridDim.y;
  const int nwg = nxy * gridDim.z;
  const int fblk = blockIdx.z * nxy + blockIdx.y * gridDim.x + blockIdx.x;
  const int qq = nwg >> 3, r8 = nwg & 7;
  const int xcd = fblk & 7, ix = fblk >> 3;
  const int swz = (xcd < r8 ? xcd * (qq + 1) : r8 * (qq + 1) + (xcd - r8) * qq) + ix;
  const int plane = swz / nxy;
  const int rem = swz % nxy;
  const int m0 = (rem % gridDim.y) * 256, n0 = (rem / gridDim.y) * 256;
  const int k0 = plane * keff;

  const int sA8 = l & 7;
  size_t aoff[2], boff[2];
#pragma unroll
  for (int j = 0; j < 2; j++) {
    const int rv = (w * 2 + j) * 8 + (l >> 3);
    const int ko = (sA8 ^ (rv & 7)) * 8;
    aoff[j] = (size_t)(m0 + ((rv >> 6) & 1) * 128 + ((rv >> 4) & 3) * 16 + (rv & 15)) * K + k0 + ko;
    boff[j] = (size_t)(n0 + ((rv >> 5) & 3) * 64 + ((rv >> 4) & 1) * 16 + (rv & 15)) * K + k0 + ko;
  }
  const int sl0 = ((lg) ^ (lr & 7)) * 8;
  const int sl1 = ((4 + lg) ^ (lr & 7)) * 8;

  f32x4 acc[8][4];
#pragma unroll
  for (int a = 0; a < 8; a++)
#pragma unroll
    for (int b = 0; b < 4; b++) acc[a][b] = (f32x4){0.f, 0.f, 0.f, 0.f};
  s16x8 af[4][2], bfr[2][2][2];

#define STG_A(bu, h, kti) { _Pragma("unroll") for (int j = 0; j < 2; j++) \
    gload_lds16(A + aoff[j] + (size_t)(h) * 64 * K + (size_t)(kti) * 64, \
                smem + (bu) * 32768 + (h) * 8192 + (w * 2 + j) * 512); }
#define STG_B(bu, h, kti) { _Pragma("unroll") for (int j = 0; j < 2; j++) \
    gload_lds16(Bt + boff[j] + (size_t)(h) * 32 * K + (size_t)(kti) * 64, \
                smem + (bu) * 32768 + 16384 + (h) * 8192 + (w * 2 + j) * 512); }
#define RD_A(bu, fmh) { const __hip_bfloat16* ab_ = smem + (bu) * 32768; \
    _Pragma("unroll") for (int f2 = 0; f2 < 4; f2++) { \
      const int ro_ = ((fmh) * 128 + wm * 64 + f2 * 16 + lr) * 64; \
      af[f2][0] = *(const s16x8*)(ab_ + ro_ + sl0); \
      af[f2][1] = *(const s16x8*)(ab_ + ro_ + sl1); } }
#define RD_BH(bu, fnh) { const __hip_bfloat16* bb_ = smem + (bu) * 32768 + 16384; \
    _Pragma("unroll") for (int f2 = 0; f2 < 2; f2++) { \
      const int ro_ = ((fnh) * 128 + wn * 32 + f2 * 16 + lr) * 64; \
      bfr[fnh][f2][0] = *(const s16x8*)(bb_ + ro_ + sl0); \
      bfr[fnh][f2][1] = *(const s16x8*)(bb_ + ro_ + sl1); } }
#define MFMA16(fmh, fnh) { __builtin_amdgcn_s_setprio(1); \
    _Pragma("unroll") for (int f2 = 0; f2 < 4; f2++) \
    _Pragma("unroll") for (int g2 = 0; g2 < 2; g2++) \
    _Pragma("unroll") for (int ks = 0; ks < 2; ks++) \
      acc[(fmh) * 4 + f2][(fnh) * 2 + g2] = __builtin_amdgcn_mfma_f32_16x16x32_bf16( \
          af[f2][ks], bfr[fnh][g2][ks], acc[(fmh) * 4 + f2][(fnh) * 2 + g2], 0, 0, 0); \
    __builtin_amdgcn_s_setprio(0); }
#define BARR() asm volatile("s_barrier" ::: "memory")
#define LGKM0() asm volatile("s_waitcnt lgkmcnt(0)" ::: "memory")
#define VMC4() asm volatile("s_waitcnt vmcnt(4)" ::: "memory")
#define VMC0() asm volatile("s_waitcnt vmcnt(0)" ::: "memory")

  STG_A(0, 0, 0); STG_A(0, 1, 0); STG_B(0, 0, 0); STG_B(0, 1, 0);
  STG_A(1, 0, 1); STG_A(1, 1, 1);
  VMC4(); BARR();

  const int niter = keff >> 7;
  for (int i = 0; i < niter; ++i) {
    const int t1 = 2 * i + 1;
    const bool more = (i + 1 < niter);
    RD_A(0, 0); RD_BH(0, 0);
    STG_B(1, 0, t1);
    BARR(); LGKM0(); MFMA16(0, 0); BARR();
    RD_BH(0, 1);
    STG_B(1, 1, t1);
    if (more) STG_A(0, 0, t1 + 1);
    BARR(); LGKM0(); MFMA16(0, 1); BARR();
    RD_A(0, 1);
    BARR(); LGKM0(); MFMA16(1, 0); BARR();
    if (more) STG_A(0, 1, t1 + 1);
    BARR(); LGKM0(); MFMA16(1, 1);
    if (more) { VMC4(); } else { VMC0(); }
    BARR();
    RD_A(1, 0); RD_BH(1, 0);
    if (more) STG_B(0, 0, t1 + 1);
    BARR(); LGKM0(); MFMA16(0, 0); BARR();
    RD_BH(1, 1);
    if (more) STG_B(0, 1, t1 + 1);
    BARR(); LGKM0(); MFMA16(0, 1); BARR();
    RD_A(1, 1);
    if (more) STG_A(1, 0, t1 + 2);
    BARR(); LGKM0(); MFMA16(1, 0); BARR();
    if (more) STG_A(1, 1, t1 + 2);
    BARR(); LGKM0(); MFMA16(1, 1);
    if (more) { VMC4(); }
    BARR();
  }
#undef STG_A
#undef STG_B
#undef RD_A
#undef RD_BH
#undef MFMA16
#undef BARR
#undef LGKM0
#undef VMC4
#undef VMC0

#pragma unroll
  for (int fm = 0; fm < 8; fm++) {
    const int rb = m0 + wm * 128 + fm * 16 + lg * 4;
#pragma unroll
    for (int fn = 0; fn < 4; fn++) {
      const int coln = wn * 64 + fn * 16 + lr;
#pragma unroll
      for (int j = 0; j < 4; j++) {
        const size_t idxo = (size_t)(rb + j) * N + n0 + coln;
        if constexpr (EPI == 4) {
          float* P = (plane == 0) ? (float*)Cv : (float*)Cv2;
          P[idxo] = acc[fm][fn][j];
        } else {
          ((__hip_bfloat16*)Cv)[idxo] = __float2bfloat16(acc[fm][fn][j]);
        }
      }
    }
  }
}

// ---------- 8-phase 256x192 bf16 GEMM (BN=192 for exact grid packing; r10) ----------
// 512 thr = 8 waves (2M x 4N); wave tile 128x48 (3 n-frags); BK=64, 2 K-tiles/iter.
// LDS 112 KiB: 2 bufs x (A 32K + B 24K). B rows 0..191 map IDENTITY to cols n0+r.
// B staged in 3 slots of 64 rows (1 gload/wave each); same row&7 XOR swizzle (48%8==0,
// 64%8==0 keep read-row&7 == lr&7). 7 loads/tile; VMC4 at ph3/ph7 leaves exactly the
// 4 next-tile A-loads outstanding (same invariant as r7/r9 kernel).
// EPI: 3 DUAL gate+up; 4 f32 split planes; 5 bf16 split Cv + plane*PSTR.
template <int EPI>
__global__ __launch_bounds__(512, 2) void k_gemm192(const __hip_bfloat16* __restrict__ A,
                                                    const __hip_bfloat16* __restrict__ Bt,
                                                    void* __restrict__ Cv,
                                                    const __hip_bfloat16* __restrict__ Bt2,
                                                    void* __restrict__ Cv2,
                                                    int N, int K, int keff) {
  __shared__ alignas(16) __hip_bfloat16 smem[57344];  // 112 KiB: buf = A 16384 + B 12288 elems
  const int t = threadIdx.x;
  const int w = t >> 6;
  const int wm = w >> 2, wn = w & 3;
  const int l = t & 63;
  const int lr = l & 15, lg = l >> 4;

  const int nxy = gridDim.x * gridDim.y;
  const int nwg = nxy * gridDim.z;
  const int fblk = blockIdx.z * nxy + blockIdx.y * gridDim.x + blockIdx.x;
  const int qq = nwg >> 3, r8 = nwg & 7;
  const int xcd = fblk & 7, ix = fblk >> 3;
  const int swz = (xcd < r8 ? xcd * (qq + 1) : r8 * (qq + 1) + (xcd - r8) * qq) + ix;
  const int plane = swz / nxy;
  const int rem = swz % nxy;
  const int m0 = (rem % gridDim.y) * 256, n0 = (rem / gridDim.y) * 192;
  const int k0 = plane * keff;

  const __hip_bfloat16* Bsrc = Bt;
  int nb0 = n0;
  if constexpr (EPI == 3) {
    if (n0 >= FFDIM) { Bsrc = Bt2; nb0 = n0 - FFDIM; }  // 9216 % 192 == 0: no straddle
  }

  const int sA8 = l & 7;
  size_t aoff[2];
#pragma unroll
  for (int j = 0; j < 2; j++) {
    const int rv = (w * 2 + j) * 8 + (l >> 3);
    const int ko = (sA8 ^ (rv & 7)) * 8;
    aoff[j] = (size_t)(m0 + ((rv >> 6) & 1) * 128 + ((rv >> 4) & 3) * 16 + (rv & 15)) * K + k0 + ko;
  }
  // B: LDS row r (0..191) holds global col nb0 + r (identity); slot c covers rows c*64..+64
  const size_t boffh = (size_t)(nb0 + w * 8 + (l >> 3)) * K + k0 + ((sA8 ^ (l >> 3)) * 8);
  const int sl0 = ((lg) ^ (lr & 7)) * 8;
  const int sl1 = ((4 + lg) ^ (lr & 7)) * 8;

  f32x4 acc[8][3];
#pragma unroll
  for (int a = 0; a < 8; a++)
#pragma unroll
    for (int b = 0; b < 3; b++) acc[a][b] = (f32x4){0.f, 0.f, 0.f, 0.f};
  s16x8 af[4][2], bfr[3][2];  // bfr[frag][ks] — all 3 frags retained per tile

#define GSTG_A(bu, h, kti) { _Pragma("unroll") for (int j = 0; j < 2; j++) \
    gload_lds16(A + aoff[j] + (size_t)(h) * 64 * K + (size_t)(kti) * 64, \
                smem + (bu) * 28672 + (h) * 8192 + (w * 2 + j) * 512); }
#define GSTG_B(bu, c, kti) \
    gload_lds16(Bsrc + boffh + (size_t)(c) * 64 * K + (size_t)(kti) * 64, \
                smem + (bu) * 28672 + 16384 + ((c) * 64 + w * 8) * 64);
#define GRD_A(bu, fmh) { const __hip_bfloat16* ab_ = smem + (bu) * 28672; \
    _Pragma("unroll") for (int f2 = 0; f2 < 4; f2++) { \
      const int ro_ = ((fmh) * 128 + wm * 64 + f2 * 16 + lr) * 64; \
      af[f2][0] = *(const s16x8*)(ab_ + ro_ + sl0); \
      af[f2][1] = *(const s16x8*)(ab_ + ro_ + sl1); } }
#define GRD_B01(bu) { const __hip_bfloat16* bb_ = smem + (bu) * 28672 + 16384; \
    _Pragma("unroll") for (int f2 = 0; f2 < 2; f2++) { \
      const int ro_ = (wn * 48 + f2 * 16 + lr) * 64; \
      bfr[f2][0] = *(const s16x8*)(bb_ + ro_ + sl0); \
      bfr[f2][1] = *(const s16x8*)(bb_ + ro_ + sl1); } }
#define GRD_B2(bu) { const __hip_bfloat16* bb_ = smem + (bu) * 28672 + 16384; \
      const int ro_ = (wn * 48 + 32 + lr) * 64; \
      bfr[2][0] = *(const s16x8*)(bb_ + ro_ + sl0); \
      bfr[2][1] = *(const s16x8*)(bb_ + ro_ + sl1); }
#define GMFMA01(fmh) { __builtin_amdgcn_s_setprio(1); \
    _Pragma("unroll") for (int f2 = 0; f2 < 4; f2++) \
    _Pragma("unroll") for (int g2 = 0; g2 < 2; g2++) \
    _Pragma("unroll") for (int ks = 0; ks < 2; ks++) \
      acc[(fmh) * 4 + f2][g2] = __builtin_amdgcn_mfma_f32_16x16x32_bf16( \
          af[f2][ks], bfr[g2][ks], acc[(fmh) * 4 + f2][g2], 0, 0, 0); \
    __builtin_amdgcn_s_setprio(0); }
#define GMFMA2(fmh) { __builtin_amdgcn_s_setprio(1); \
    _Pragma("unroll") for (int f2 = 0; f2 < 4; f2++) \
    _Pragma("unroll") for (int ks = 0; ks < 2; ks++) \
      acc[(fmh) * 4 + f2][2] = __builtin_amdgcn_mfma_f32_16x16x32_bf16( \
          af[f2][ks], bfr[2][ks], acc[(fmh) * 4 + f2][2], 0, 0, 0); \
    __builtin_amdgcn_s_setprio(0); }
#define BARR() asm volatile("s_barrier" ::: "memory")
#define LGKM0() asm volatile("s_waitcnt lgkmcnt(0)" ::: "memory")
#define VMC4() asm volatile("s_waitcnt vmcnt(4)" ::: "memory")
#define VMC0() asm volatile("s_waitcnt vmcnt(0)" ::: "memory")

  // prologue: t0 full (A 4 + B 3 = 7 loads) + t1 A (4) -> VMC4 forces t0 landed
  GSTG_A(0, 0, 0); GSTG_A(0, 1, 0);
  GSTG_B(0, 0, 0); GSTG_B(0, 1, 0); GSTG_B(0, 2, 0);
  GSTG_A(1, 0, 1); GSTG_A(1, 1, 1);
  VMC4(); BARR();

  const int niter = keff >> 7;  // 2 tiles/iter (requires keff % 128 == 0)
  for (int i = 0; i < niter; ++i) {
    const int t1 = 2 * i + 1;
    const bool more = (i + 1 < niter);
    // p0: T0 (fmh0, fng01); stage B0,B1(t1)
    GRD_A(0, 0); GRD_B01(0);
    GSTG_B(1, 0, t1); GSTG_B(1, 1, t1);
    BARR(); LGKM0(); GMFMA01(0); BARR();
    // p1: (fmh0, fng2); stage B2(t1) + A0(t0')
    GRD_B2(0);
    GSTG_B(1, 2, t1);
    if (more) GSTG_A(0, 0, t1 + 1);
    BARR(); LGKM0(); GMFMA2(0); BARR();
    // p2: (fmh1, fng01) — B retained
    GRD_A(0, 1);
    BARR(); LGKM0(); GMFMA01(1); BARR();
    // p3: (fmh1, fng2); stage A1(t0'); counted wait: t1 landed for p4
    if (more) GSTG_A(0, 1, t1 + 1);
    BARR(); LGKM0(); GMFMA2(1);
    if (more) { VMC4(); } else { VMC0(); }
    BARR();
    // p4: T1 (fmh0, fng01); stage B0,B1(t0')
    GRD_A(1, 0); GRD_B01(1);
    if (more) { GSTG_B(0, 0, t1 + 1); GSTG_B(0, 1, t1 + 1); }
    BARR(); LGKM0(); GMFMA01(0); BARR();
    // p5: (fmh0, fng2); stage B2(t0') + A0(t1')
    GRD_B2(1);
    if (more) { GSTG_B(0, 2, t1 + 1); GSTG_A(1, 0, t1 + 2); }
    BARR(); LGKM0(); GMFMA2(0); BARR();
    // p6: (fmh1, fng01)
    GRD_A(1, 1);
    BARR(); LGKM0(); GMFMA01(1); BARR();
    // p7: (fmh1, fng2); stage A1(t1'); counted wait: t0' landed for next p0
    if (more) GSTG_A(1, 1, t1 + 2);
    BARR(); LGKM0(); GMFMA2(1);
    if (more) { VMC4(); }
    BARR();
  }
#undef GSTG_A
#undef GSTG_B
#undef GRD_A
#undef GRD_B01
#undef GRD_B2
#undef GMFMA01
#undef GMFMA2
#undef BARR
#undef LGKM0
#undef VMC4
#undef VMC0

  // epilogue: C/D col = lane&15, row = (lane>>4)*4 + reg
  __hip_bfloat16* Cw = nullptr;
  int cbase = n0, cstride = N;
  if constexpr (EPI == 3) {
    Cw = (__hip_bfloat16*)((n0 < FFDIM) ? Cv : Cv2);
    cbase = (n0 < FFDIM) ? n0 : n0 - FFDIM;
    cstride = FFDIM;
  }
#pragma unroll
  for (int fm = 0; fm < 8; fm++) {
    const int rb = m0 + wm * 128 + fm * 16 + lg * 4;
#pragma unroll
    for (int fn = 0; fn < 3; fn++) {
      const int coln = wn * 48 + fn * 16 + lr;
#pragma unroll
      for (int j = 0; j < 4; j++) {
        if constexpr (EPI == 3) {
          Cw[(size_t)(rb + j) * cstride + cbase + coln] = __float2bfloat16(acc[fm][fn][j]);
        } else if constexpr (EPI == 4) {
          float* P = (plane == 0) ? (float*)Cv : (float*)Cv2;
          P[(size_t)(rb + j) * N + n0 + coln] = acc[fm][fn][j];
        } else {  // EPI == 5
          ((__hip_bfloat16*)Cv)[(size_t)plane * PSTR + (size_t)(rb + j) * N + n0 + coln] =
              __float2bfloat16(acc[fm][fn][j]);
        }
      }
    }
  }
}

// ---------------- gelu(g) * u, all bf16, vectorized x8; o may alias g ----------------
__global__ void k_gelu_mul2(const __hip_bfloat16* __restrict__ g, const __hip_bfloat16* __restrict__ u,
                            __hip_bfloat16* __restrict__ o, int n8) {
  const int st = gridDim.x * blockDim.x;
  for (int i = blockIdx.x * blockDim.x + threadIdx.x; i < n8; i += st) {
    s16x8 gv = *(const s16x8*)(g + (size_t)i * 8);
    s16x8 uv = *(const s16x8*)(u + (size_t)i * 8);
    s16x8 ov;
#pragma unroll
    for (int j = 0; j < 8; j++) {
      const float x = __uint_as_float(((uint32_t)(uint16_t)gv[j]) << 16);
      const float uu = __uint_as_float(((uint32_t)(uint16_t)uv[j]) << 16);
      const float tt = tanhf(0.7978845608028654f * (x + 0.044715f * x * x * x));
      const float r = 0.5f * x * (1.f + tt) * uu;
      ov[j] = (short)(__hip_bfloat16_raw(__float2bfloat16(r)).x);
    }
    *(s16x8*)(o + (size_t)i * 8) = ov;
  }
}

// ------ rope + split + scale: qkv = P0 + P1 (two f32 partial planes) -> Q/K bf16 head-major ------
__global__ void k_rope_split(const float* __restrict__ p0, const float* __restrict__ p1,
                             const float* __restrict__ cosb, const float* __restrict__ sinb,
                             __hip_bfloat16* __restrict__ qo, __hip_bfloat16* __restrict__ ko) {
  const int s = blockIdx.x;
  const float* r0 = p0 + (size_t)s * QKVN;
  const float* r1 = p1 + (size_t)s * QKVN;
  const float* cr = cosb + (size_t)s * 128;
  const float* sr = sinb + (size_t)s * 128;
  for (int idx = threadIdx.x; idx < (NHEAD + NKVH) * 128; idx += 256) {
    const int hh = idx >> 7, d = idx & 127;
    const float cv = cr[d], sv = sr[d];
    if (hh < NHEAD) {
      const float x1 = r0[hh * DHEAD + d] + r1[hh * DHEAD + d];
      const float x2 = r0[hh * DHEAD + 128 + d] + r1[hh * DHEAD + 128 + d];
      const size_t base = ((size_t)hh * S_LEN + s) * DHEAD;
      qo[base + d]       = __float2bfloat16((x1 * cv - x2 * sv) * QSCALE);
      qo[base + 128 + d] = __float2bfloat16((x1 * sv + x2 * cv) * QSCALE);
    } else {
      const int kv = hh - NHEAD;
      const int o1 = NHEAD * DHEAD + kv * DHEAD + d;
      const float x1 = r0[o1] + r1[o1];
      const float x2 = r0[o1 + 128] + r1[o1 + 128];
      const size_t base = ((size_t)kv * S_LEN + s) * DHEAD;
      ko[base + d]       = __float2bfloat16(x1 * cv - x2 * sv);
      ko[base + 128 + d] = __float2bfloat16(x1 * sv + x2 * cv);
    }
  }
}

// -------- V extract + transpose from 2 partial planes: -> Vt[kv][256 d][2048 s] bf16 --------
__global__ __launch_bounds__(256) void k_vsplit_t(const float* __restrict__ p0,
                                                  const float* __restrict__ p1,
                                                  __hip_bfloat16* __restrict__ vt) {
  __shared__ float tile[64][260];
  const int s0 = blockIdx.x * 64, kv = blockIdx.y;
  const int t = threadIdx.x;
  const int rr = t >> 6, c4 = t & 63;
#pragma unroll
  for (int p = 0; p < 16; p++) {
    const int row = rr + p * 4;
    const size_t go = (size_t)(s0 + row) * QKVN + (NHEAD + NKVH) * DHEAD + kv * DHEAD + c4 * 4;
    const float4 v0 = *(const float4*)(p0 + go);
    const float4 v1 = *(const float4*)(p1 + go);
    float4 v;
    v.x = v0.x + v1.x; v.y = v0.y + v1.y; v.z = v0.z + v1.z; v.w = v0.w + v1.w;
    *(float4*)(&tile[row][c4 * 4]) = v;
  }
  __syncthreads();
  const int c = t & 31, dr = t >> 5;
#pragma unroll
  for (int p = 0; p < 32; p++) {
    const int d = dr + p * 8;
    __hip_bfloat162 pr;
    pr.x = __float2bfloat16(tile[2 * c][d]);
    pr.y = __float2bfloat16(tile[2 * c + 1][d]);
    *(__hip_bfloat162*)(vt + ((size_t)kv * DHEAD + d) * S_LEN + s0 + 2 * c) = pr;
  }
}

// ---------------- MFMA flash attention: sliding-window causal + softcap ----------------
__global__ __launch_bounds__(256) void k_attn_mfma(const __hip_bfloat16* __restrict__ Q,
                                                   const __hip_bfloat16* __restrict__ Kb,
                                                   const __hip_bfloat16* __restrict__ Vt,
                                                   __hip_bfloat16* __restrict__ O) {
  __shared__ alignas(16) __hip_bfloat16 Ks[64 * 264];
  __shared__ alignas(16) __hip_bfloat16 Vs[256 * 72];
  __shared__ alignas(16) __hip_bfloat16 Ps[64 * 72];
  const int h = blockIdx.y, kvh = h >> 1;
  const int q0 = blockIdx.x * 64;
  const int t = threadIdx.x;
  const int wq = t >> 6;
  const int l = t & 63;
  const int lr = l & 15, lg = l >> 4;

  s16x8 qf[8];
  {
    const __hip_bfloat16* qrow = Q + ((size_t)h * S_LEN + q0 + wq * 16 + lr) * DHEAD;
#pragma unroll
    for (int ks = 0; ks < 8; ks++) qf[ks] = *(const s16x8*)(qrow + ks * 32 + lg * 8);
  }
  f32x4 acc[16];
#pragma unroll
  for (int i = 0; i < 16; i++) acc[i] = (f32x4){0.f, 0.f, 0.f, 0.f};
  float rsum[4] = {0.f, 0.f, 0.f, 0.f};

  int lo = q0 - WINM1;
  if (lo < 0) lo = 0;
  lo &= ~63;
  const int qrow_base = q0 + wq * 16 + lg * 4;

  for (int kc = lo; kc <= q0; kc += 64) {
#pragma unroll
    for (int p = 0; p < 8; p++) {
      const int idx = t + p * 256;
      const int row = idx >> 5, c16 = idx & 31;
      s16x8 v = *(const s16x8*)(Kb + ((size_t)kvh * S_LEN + kc + row) * DHEAD + c16 * 8);
      *(s16x8*)(Ks + row * 264 + c16 * 8) = v;
    }
#pragma unroll
    for (int p = 0; p < 8; p++) {
      const int idx = t + p * 256;
      const int d = idx >> 3, ch = idx & 7;
      s16x8 v = *(const s16x8*)(Vt + ((size_t)kvh * DHEAD + d) * S_LEN + kc + ch * 8);
      *(s16x8*)(Vs + d * 72 + ch * 8) = v;
    }
    __syncthreads();

    f32x4 sc[4];
#pragma unroll
    for (int fq = 0; fq < 4; fq++) {
      sc[fq] = (f32x4){0.f, 0.f, 0.f, 0.f};
#pragma unroll
      for (int ks = 0; ks < 8; ks++) {
        s16x8 bfr = *(const s16x8*)(Ks + (fq * 16 + lr) * 264 + ks * 32 + lg * 8);
        sc[fq] = __builtin_amdgcn_mfma_f32_16x16x32_bf16(qf[ks], bfr, sc[fq], 0, 0, 0);
      }
    }
#pragma unroll
    for (int fq = 0; fq < 4; fq++) {
      const int k = kc + fq * 16 + lr;
#pragma unroll
      for (int j = 0; j < 4; j++) {
        const int qw = qrow_base + j;
        float p = 0.f;
        if (k <= qw && qw - k <= WINM1) {
          const float s = sc[fq][j];
          const float u = exp2f(s * 0.057707801635558534f);
          const float arg = 72.134752044448169f -
                            144.26950408889634f * __builtin_amdgcn_rcpf(u + 1.f);
          p = exp2f(arg);
        }
        const __hip_bfloat16 pb = __float2bfloat16(p);
        Ps[(wq * 16 + lg * 4 + j) * 72 + fq * 16 + lr] = pb;
        rsum[j] += __bfloat162float(pb);
      }
    }
#pragma unroll
    for (int ks2 = 0; ks2 < 2; ks2++) {
      s16x8 pa = *(const s16x8*)(Ps + (wq * 16 + lr) * 72 + ks2 * 32 + lg * 8);
#pragma unroll
      for (int f2 = 0; f2 < 16; f2++) {
        s16x8 vb = *(const s16x8*)(Vs + (f2 * 16 + lr) * 72 + ks2 * 32 + lg * 8);
        acc[f2] = __builtin_amdgcn_mfma_f32_16x16x32_bf16(pa, vb, acc[f2], 0, 0, 0);
      }
    }
    __syncthreads();
  }
#pragma unroll
  for (int j = 0; j < 4; j++) {
    float s = rsum[j];
#pragma unroll
    for (int off = 1; off < 16; off <<= 1) s += __shfl_xor(s, off, 64);
    rsum[j] = 1.f / s;
  }
#pragma unroll
  for (int f2 = 0; f2 < 16; f2++)
#pragma unroll
    for (int j = 0; j < 4; j++)
      O[(size_t)(qrow_base + j) * ODIM + h * DHEAD + f2 * 16 + lr] =
          __float2bfloat16(acc[f2][j] * rsum[j]);
}

// ---------------- launcher ----------------
extern "C" void kernel_launch(void* const* d_in, const int* in_sizes, int n_in,
                              void* d_out, int out_size, void* d_ws, size_t ws_size,
                              hipStream_t stream) {
  const float* hidden  = (const float*)d_in[0];
  const float* qkv_w   = (const float*)d_in[1];
  const float* o_w     = (const float*)d_in[2];
  const float* gate_w  = (const float*)d_in[3];
  const float* up_w    = (const float*)d_in[4];
  const float* down_w  = (const float*)d_in[5];
  const float* in_ln   = (const float*)d_in[6];
  const float* post_attn_ln = (const float*)d_in[7];
  const float* pre_ffw_ln   = (const float*)d_in[8];
  const float* post_ffw_ln  = (const float*)d_in[9];
  const float* cosb    = (const float*)d_in[10];
  const float* sinb    = (const float*)d_in[11];
  float* out = (float*)d_out;
  char* ws = (char*)d_ws;

  // ---- workspace layout (bytes) ----
  const size_t OFF_W   = 0;          // 42.47 MB reusable transposed-weight slot
  const size_t OFF_HF  = 42467328;   // h residual f32
  const size_t OFF_X   = 61341696;   // x_norm bf16
  const size_t OFF_S1  = 70778880;   // 37.75 MB
  const size_t OFF_S2  = 108527616;  // 37.75 MB
  const size_t NEED    = 146276352;
  const size_t OFF_W2  = 146276352;  // 42.47 MB (up^T; qkv partial plane1; down partial tail)
  const size_t NEED_F  = 188743680;

  if (ws_size < NEED) {
    k_fill<<<1024, 256, 0, stream>>>(out, 100000.0f + (float)(ws_size >> 20), (size_t)out_size);
    return;
  }
  const bool FUSED = (ws_size >= NEED_F);

  __hip_bfloat16* W    = (__hip_bfloat16*)(ws + OFF_W);
  __hip_bfloat16* W2   = (__hip_bfloat16*)(ws + OFF_W2);
  float*          Hf   = (float*)(ws + OFF_HF);
  __hip_bfloat16* Xb   = (__hip_bfloat16*)(ws + OFF_X);
  __hip_bfloat16* GATEB= (__hip_bfloat16*)(ws + OFF_S1);
  __hip_bfloat16* UPB  = (__hip_bfloat16*)(ws + OFF_S2);
  __hip_bfloat16* Qb   = (__hip_bfloat16*)(ws + OFF_S2);
  __hip_bfloat16* Kb   = (__hip_bfloat16*)(ws + OFF_S2 + 8388608);
  __hip_bfloat16* Vtb  = (__hip_bfloat16*)(ws + OFF_S2 + 12582912);
  __hip_bfloat16* ATTN = (__hip_bfloat16*)(ws + OFF_S2 + 29360128);

  if (FUSED) {
    float* QKV0 = (float*)(ws + OFF_S1);
    float* QKV1 = (float*)(ws + OFF_W2);
    float* PROJ = (float*)(ws + OFF_S1);
    __hip_bfloat16* DPART = (__hip_bfloat16*)(ws + OFF_S2);  // 8 bf16 planes (75.5 MB)

    // 1. qkv^T -> W ; x = rmsnorm(hidden) -> Xb ; qkv = Xb @ W^T (256^2 8-phase, split-K=2)
    k_transpose_bf16<<<dim3(QKVN / 32, HIDDEN / 32), 256, 0, stream>>>(qkv_w, W, HIDDEN, QKVN);
    k_rmsnorm<1, false, false, true><<<S_LEN, 256, 0, stream>>>(hidden, in_ln, nullptr, Xb);
    k_gemm8<4><<<dim3(QKVN / 256, S_LEN / 256, 2), 512, 0, stream>>>(
        Xb, W, QKV0, nullptr, nullptr, QKV1, QKVN, HIDDEN, HIDDEN / 2);
    // 2. rope+split Q/K ; V extract+transpose
    k_rope_split<<<S_LEN, 256, 0, stream>>>(QKV0, QKV1, cosb, sinb, Qb, Kb);
    k_vsplit_t<<<dim3(S_LEN / 64, NKVH), 256, 0, stream>>>(QKV0, QKV1, Vtb);
    // 3. attention -> ATTN (bf16)
    k_attn_mfma<<<dim3(S_LEN / 64, NHEAD), 256, 0, stream>>>(Qb, Kb, Vtb, ATTN);
    // 4. o^T -> W ; proj = ATTN @ W^T (192-col 8-phase, split-K=2 -> 192 blocks, 1 round)
    k_transpose_bf16<<<dim3(HIDDEN / 32, ODIM / 32), 256, 0, stream>>>(o_w, W, ODIM, HIDDEN);
    k_gemm192<4><<<dim3(HIDDEN / 192, S_LEN / 256, 2), 512, 0, stream>>>(
        ATTN, W, PROJ, nullptr, PROJ + PSTR, HIDDEN, ODIM, ODIM / 2);
    // 5. fused: h = hidden + rmsnorm(proj) -> Hf ; x2 = rmsnorm(h) -> Xb
    k_rmsnorm2<<<S_LEN, 256, 0, stream>>>(PROJ, post_attn_ln, hidden, pre_ffw_ln, Hf, Xb);
    // 6. gate^T -> W, up^T -> W2; fused gate+up GEMM (768 blocks = exactly 3 rounds)
    k_transpose_bf16<<<dim3(FFDIM / 32, HIDDEN / 32), 256, 0, stream>>>(gate_w, W, HIDDEN, FFDIM);
    k_transpose_bf16<<<dim3(FFDIM / 32, HIDDEN / 32), 256, 0, stream>>>(up_w, W2, HIDDEN, FFDIM);
    k_gemm192<3><<<dim3((2 * FFDIM) / 192, S_LEN / 256, 1), 512, 0, stream>>>(
        Xb, W, GATEB, W2, UPB, FFDIM, HIDDEN, HIDDEN);
    // 7. act = gelu(gate)*up, in-place over S1
    k_gelu_mul2<<<2048, 256, 0, stream>>>(GATEB, UPB, GATEB, (S_LEN * FFDIM) / 8);
    // 8. down^T -> W ; y-partials = ACT @ W^T (768 blocks = 3 rounds, split-K=8, bf16 planes)
    k_transpose_bf16<<<dim3(HIDDEN / 32, FFDIM / 32), 256, 0, stream>>>(down_w, W, FFDIM, HIDDEN);
    k_gemm192<5><<<dim3(HIDDEN / 192, S_LEN / 256, 8), 512, 0, stream>>>(
        GATEB, W, DPART, nullptr, nullptr, HIDDEN, FFDIM, FFDIM / 8);
    // 9. out = h + rmsnorm(sum of 8 partials)
    k_rmsnorm<8, true, true, false><<<S_LEN, 256, 0, stream>>>(DPART, post_ffw_ln, Hf, out);
  } else {
    // fallback: no split-K (zero plane1 via Hf)
    float* QKV = (float*)(ws + OFF_S1);
    float* PROJ = (float*)(ws + OFF_S2);
    k_transpose_bf16<<<dim3(QKVN / 32, HIDDEN / 32), 256, 0, stream>>>(qkv_w, W, HIDDEN, QKVN);
    k_rmsnorm<1, false, false, true><<<S_LEN, 256, 0, stream>>>(hidden, in_ln, nullptr, Xb);
    k_gemm_bt<0><<<dim3(QKVN / 128, S_LEN / 128), 256, 0, stream>>>(Xb, W, QKV, nullptr, QKVN, HIDDEN);
    k_fill<<<1024, 256, 0, stream>>>(Hf, 0.f, PSTR);
    k_rope_split<<<S_LEN, 256, 0, stream>>>(QKV, Hf, cosb, sinb, Qb, Kb);
    k_vsplit_t<<<dim3(S_LEN / 64, NKVH), 256, 0, stream>>>(QKV, Hf, Vtb);
    k_attn_mfma<<<dim3(S_LEN / 64, NHEAD), 256, 0, stream>>>(Qb, Kb, Vtb, ATTN);
    k_transpose_bf16<<<dim3(HIDDEN / 32, ODIM / 32), 256, 0, stream>>>(o_w, W, ODIM, HIDDEN);
    k_gemm_bt<0><<<dim3(HIDDEN / 128, S_LEN / 128), 256, 0, stream>>>(ATTN, W, PROJ, nullptr, HIDDEN, ODIM);
    k_rmsnorm<1, false, true, false><<<S_LEN, 256, 0, stream>>>(PROJ, post_attn_ln, hidden, Hf);
    k_rmsnorm<1, false, false, true><<<S_LEN, 256, 0, stream>>>(Hf, pre_ffw_ln, nullptr, Xb);
    k_transpose_bf16<<<dim3(FFDIM / 32, HIDDEN / 32), 256, 0, stream>>>(gate_w, W, HIDDEN, FFDIM);
    k_gemm_bt<1><<<dim3(FFDIM / 128, S_LEN / 128), 256, 0, stream>>>(Xb, W, GATEB, nullptr, FFDIM, HIDDEN);
    __hip_bfloat16* ACT = (__hip_bfloat16*)(ws + OFF_S2);
    k_transpose_bf16<<<dim3(FFDIM / 32, HIDDEN / 32), 256, 0, stream>>>(up_w, W, HIDDEN, FFDIM);
    k_gemm_bt<2><<<dim3(FFDIM / 128, S_LEN / 128), 256, 0, stream>>>(Xb, W, ACT, GATEB, FFDIM, HIDDEN);
    float* Yf = (float*)(ws + OFF_S1);
    k_transpose_bf16<<<dim3(HIDDEN / 32, FFDIM / 32), 256, 0, stream>>>(down_w, W, FFDIM, HIDDEN);
    k_gemm_bt<0><<<dim3(HIDDEN / 128, S_LEN / 128), 256, 0, stream>>>(ACT, W, Yf, nullptr, HIDDEN, FFDIM);
    k_rmsnorm<1, false, true, false><<<S_LEN, 256, 0, stream>>>(Yf, post_ffw_ln, Hf, out);
  }
}

// Round 12
// 635.654 us; speedup vs baseline: 1.1092x; 1.0190x over previous
//
#include <hip/hip_runtime.h>
#include <hip/hip_bf16.h>
#include <cstdint>
#include <cstddef>

// ---------------- constants ----------------
#define S_LEN  2048
#define HIDDEN 2304
#define NHEAD  8
#define NKVH   4
#define DHEAD  256
#define FFDIM  9216
#define QKVN   4096   // (H + 2*KV) * D
#define ODIM   2048   // H * D
#define WINM1  1023
#define QSCALE 0.0625f
#define CAPF   50.0f
#define PSTR   ((size_t)S_LEN * HIDDEN)   // partial-plane stride (elements)

typedef __attribute__((ext_vector_type(4))) float f32x4;
typedef __attribute__((ext_vector_type(8))) short s16x8;
typedef __attribute__((ext_vector_type(4))) short s16x4;

__device__ __forceinline__ short bfr16(float x) {
  return (short)__hip_bfloat16_raw(__float2bfloat16(x)).x;
}

// async global->LDS 16B copy; lptr must be wave-uniform, HW adds lane*16
__device__ __forceinline__ void gload_lds16(const void* gptr, void* lptr) {
  __builtin_amdgcn_global_load_lds(
      (const __attribute__((address_space(1))) unsigned int*)gptr,
      (__attribute__((address_space(3))) unsigned int*)lptr, 16, 0, 0);
}

// ---------------- diagnostic fill (ws too small): value encodes ws MiB ----------------
__global__ void k_fill(float* p, float v, size_t n) {
  size_t i = (size_t)blockIdx.x * blockDim.x + threadIdx.x;
  size_t st = (size_t)gridDim.x * blockDim.x;
  for (; i < n; i += st) p[i] = v;
}

// ---------------- f32 [R][C] -> bf16 [C][R], vectorized (r12: full 32-row coverage) ----------------
// block: 64 cols x 32 rows. read: 2x float4/thread (rows t>>4 and +16); write: s16x8.
__global__ __launch_bounds__(256) void k_transpose_bf16(const float* __restrict__ in,
                                                        __hip_bfloat16* __restrict__ out,
                                                        int R, int C) {
  __shared__ float tile[32][65];  // odd stride: column reads conflict-free
  const int c0 = blockIdx.x * 64, r0 = blockIdx.y * 32;
  const int t = threadIdx.x;
#pragma unroll
  for (int p = 0; p < 2; p++) {
    const int row = (t >> 4) + p * 16, c4 = (t & 15) * 4;
    const float4 v = *(const float4*)(in + (size_t)(r0 + row) * C + c0 + c4);
    tile[row][c4] = v.x; tile[row][c4 + 1] = v.y; tile[row][c4 + 2] = v.z; tile[row][c4 + 3] = v.w;
  }
  __syncthreads();
  {
    const int c = t >> 2, rq = (t & 3) * 8;
    s16x8 o;
#pragma unroll
    for (int j = 0; j < 8; j++) o[j] = bfr16(tile[rq + j][c]);
    *(s16x8*)(out + (size_t)(c0 + c) * R + r0 + rq) = o;
  }
}

// ------ rmsnorm over sum of NP planes; optional residual; f32/bf16 out (vectorized) ------
template <int NP, bool INBF16, bool ADD, bool BF16OUT>
__global__ void k_rmsnorm(const void* __restrict__ xv, const float* __restrict__ w,
                          const float* __restrict__ res, void* __restrict__ outv) {
  const int row = blockIdx.x;
  __shared__ float xs[HIDDEN];
  __shared__ float red[4];
  __shared__ float srstd;
  float ss = 0.f;
  if constexpr (INBF16) {
    const __hip_bfloat16* xb = (const __hip_bfloat16*)xv;
    for (int g = threadIdx.x; g < HIDDEN / 8; g += 256) {
      float v[8] = {0.f, 0.f, 0.f, 0.f, 0.f, 0.f, 0.f, 0.f};
#pragma unroll
      for (int p = 0; p < NP; p++) {
        const s16x8 pv = *(const s16x8*)(xb + (size_t)p * PSTR + (size_t)row * HIDDEN + g * 8);
#pragma unroll
        for (int j = 0; j < 8; j++)
          v[j] += __uint_as_float(((uint32_t)(uint16_t)pv[j]) << 16);
      }
#pragma unroll
      for (int j = 0; j < 8; j++) { xs[g * 8 + j] = v[j]; ss += v[j] * v[j]; }
    }
  } else {
    const float* xf = (const float*)xv;
    for (int g = threadIdx.x; g < HIDDEN / 4; g += 256) {
      float v[4] = {0.f, 0.f, 0.f, 0.f};
#pragma unroll
      for (int p = 0; p < NP; p++) {
        const float4 pv = *(const float4*)(xf + (size_t)p * PSTR + (size_t)row * HIDDEN + g * 4);
        v[0] += pv.x; v[1] += pv.y; v[2] += pv.z; v[3] += pv.w;
      }
#pragma unroll
      for (int j = 0; j < 4; j++) { xs[g * 4 + j] = v[j]; ss += v[j] * v[j]; }
    }
  }
#pragma unroll
  for (int off = 32; off >= 1; off >>= 1) ss += __shfl_down(ss, off);
  if ((threadIdx.x & 63) == 0) red[threadIdx.x >> 6] = ss;
  __syncthreads();
  if (threadIdx.x == 0)
    srstd = rsqrtf((red[0] + red[1] + red[2] + red[3]) / (float)HIDDEN + 1e-6f);
  __syncthreads();
  const float rstd = srstd;
  for (int g = threadIdx.x; g < HIDDEN / 4; g += 256) {
    const float4 w4 = *(const float4*)(w + g * 4);
    float v[4];
    v[0] = xs[g * 4 + 0] * rstd * (1.f + w4.x);
    v[1] = xs[g * 4 + 1] * rstd * (1.f + w4.y);
    v[2] = xs[g * 4 + 2] * rstd * (1.f + w4.z);
    v[3] = xs[g * 4 + 3] * rstd * (1.f + w4.w);
    if constexpr (ADD) {
      const float4 r4 = *(const float4*)(res + (size_t)row * HIDDEN + g * 4);
      v[0] += r4.x; v[1] += r4.y; v[2] += r4.z; v[3] += r4.w;
    }
    if constexpr (BF16OUT) {
      s16x4 o;
#pragma unroll
      for (int j = 0; j < 4; j++) o[j] = bfr16(v[j]);
      *(s16x4*)((__hip_bfloat16*)outv + (size_t)row * HIDDEN + g * 4) = o;
    } else {
      float4 o; o.x = v[0]; o.y = v[1]; o.z = v[2]; o.w = v[3];
      *(float4*)((float*)outv + (size_t)row * HIDDEN + g * 4) = o;
    }
  }
}

// ---- fused: h = res + rmsnorm(P0+P1)*(1+w1) -> Hf(f32); x2 = rmsnorm(h)*(1+w2) -> Xb(bf16) ----
__global__ void k_rmsnorm2(const float* __restrict__ planes, const float* __restrict__ w1,
                           const float* __restrict__ res, const float* __restrict__ w2,
                           float* __restrict__ hf, __hip_bfloat16* __restrict__ xb) {
  const int row = blockIdx.x;
  __shared__ float xs[HIDDEN];
  __shared__ float red[4];
  __shared__ float srstd;
  float ss = 0.f;
  for (int g = threadIdx.x; g < HIDDEN / 4; g += 256) {
    const float4 a = *(const float4*)(planes + (size_t)row * HIDDEN + g * 4);
    const float4 b = *(const float4*)(planes + PSTR + (size_t)row * HIDDEN + g * 4);
    float v[4] = {a.x + b.x, a.y + b.y, a.z + b.z, a.w + b.w};
#pragma unroll
    for (int j = 0; j < 4; j++) { xs[g * 4 + j] = v[j]; ss += v[j] * v[j]; }
  }
#pragma unroll
  for (int off = 32; off >= 1; off >>= 1) ss += __shfl_down(ss, off);
  if ((threadIdx.x & 63) == 0) red[threadIdx.x >> 6] = ss;
  __syncthreads();
  if (threadIdx.x == 0)
    srstd = rsqrtf((red[0] + red[1] + red[2] + red[3]) / (float)HIDDEN + 1e-6f);
  __syncthreads();
  const float rstd1 = srstd;
  float ss2 = 0.f;
  for (int g = threadIdx.x; g < HIDDEN / 4; g += 256) {
    const float4 w4 = *(const float4*)(w1 + g * 4);
    const float4 r4 = *(const float4*)(res + (size_t)row * HIDDEN + g * 4);
    float h[4];
    h[0] = r4.x + xs[g * 4 + 0] * rstd1 * (1.f + w4.x);
    h[1] = r4.y + xs[g * 4 + 1] * rstd1 * (1.f + w4.y);
    h[2] = r4.z + xs[g * 4 + 2] * rstd1 * (1.f + w4.z);
    h[3] = r4.w + xs[g * 4 + 3] * rstd1 * (1.f + w4.w);
    float4 o; o.x = h[0]; o.y = h[1]; o.z = h[2]; o.w = h[3];
    *(float4*)(hf + (size_t)row * HIDDEN + g * 4) = o;
#pragma unroll
    for (int j = 0; j < 4; j++) { xs[g * 4 + j] = h[j]; ss2 += h[j] * h[j]; }
  }
#pragma unroll
  for (int off = 32; off >= 1; off >>= 1) ss2 += __shfl_down(ss2, off);
  if ((threadIdx.x & 63) == 0) red[threadIdx.x >> 6] = ss2;
  __syncthreads();
  if (threadIdx.x == 0)
    srstd = rsqrtf((red[0] + red[1] + red[2] + red[3]) / (float)HIDDEN + 1e-6f);
  __syncthreads();
  const float rstd2 = srstd;
  for (int g = threadIdx.x; g < HIDDEN / 4; g += 256) {
    const float4 w4 = *(const float4*)(w2 + g * 4);
    s16x4 o;
    o[0] = bfr16(xs[g * 4 + 0] * rstd2 * (1.f + w4.x));
    o[1] = bfr16(xs[g * 4 + 1] * rstd2 * (1.f + w4.y));
    o[2] = bfr16(xs[g * 4 + 2] * rstd2 * (1.f + w4.z));
    o[3] = bfr16(xs[g * 4 + 3] * rstd2 * (1.f + w4.w));
    *(s16x4*)(xb + (size_t)row * HIDDEN + g * 4) = o;
  }
}

// ---------------- bf16 GEMM (m97 structure + XCD swizzle): C = A * Bt^T ----------------
template <int EPI>
__global__ __launch_bounds__(256) void k_gemm_bt(const __hip_bfloat16* __restrict__ A,
                                                 const __hip_bfloat16* __restrict__ Bt,
                                                 void* __restrict__ Cv,
                                                 const __hip_bfloat16* __restrict__ G,
                                                 int N, int K) {
  __shared__ alignas(16) __hip_bfloat16 sA[128 * 64];
  __shared__ alignas(16) __hip_bfloat16 sB[128 * 64];
  const int t = threadIdx.x;
  const int w = t >> 6;
  const int wm = w >> 1, wn = w & 1;
  const int nwg = gridDim.x * gridDim.y;
  const int fblk = blockIdx.y * gridDim.x + blockIdx.x;
  const int qq = nwg >> 3, r8 = nwg & 7;
  const int xcd = fblk & 7, ix = fblk >> 3;
  const int swz = (xcd < r8 ? xcd * (qq + 1) : r8 * (qq + 1) + (xcd - r8) * qq) + ix;
  const int m0 = (swz % gridDim.y) * 128, n0 = (swz / gridDim.y) * 128;
  const int lr = t & 15, lg = (t & 63) >> 4;
  const int srow = t >> 3, sc8 = t & 7;

  f32x4 acc[4][4];
#pragma unroll
  for (int a = 0; a < 4; a++)
#pragma unroll
    for (int b = 0; b < 4; b++) acc[a][b] = (f32x4){0.f, 0.f, 0.f, 0.f};

  for (int kt = 0; kt < K; kt += 64) {
#pragma unroll
    for (int i = 0; i < 4; i++) {
      const __hip_bfloat16* g = A + (size_t)(m0 + i * 32 + srow) * K + kt + sc8 * 8;
      gload_lds16(g, sA + (size_t)(i * 256 + w * 64) * 8);
    }
#pragma unroll
    for (int i = 0; i < 4; i++) {
      const __hip_bfloat16* g = Bt + (size_t)(n0 + i * 32 + srow) * K + kt + sc8 * 8;
      gload_lds16(g, sB + (size_t)(i * 256 + w * 64) * 8);
    }
    __syncthreads();
#pragma unroll
    for (int ks = 0; ks < 2; ks++) {
      s16x8 af[4], bfr[4];
#pragma unroll
      for (int fm = 0; fm < 4; fm++)
        af[fm] = *reinterpret_cast<const s16x8*>(sA + (wm * 64 + fm * 16 + lr) * 64 + ks * 32 + lg * 8);
#pragma unroll
      for (int fn = 0; fn < 4; fn++)
        bfr[fn] = *reinterpret_cast<const s16x8*>(sB + (wn * 64 + fn * 16 + lr) * 64 + ks * 32 + lg * 8);
#pragma unroll
      for (int fm = 0; fm < 4; fm++)
#pragma unroll
        for (int fn = 0; fn < 4; fn++)
          acc[fm][fn] = __builtin_amdgcn_mfma_f32_16x16x32_bf16(af[fm], bfr[fn], acc[fm][fn], 0, 0, 0);
    }
    __syncthreads();
  }
#pragma unroll
  for (int fm = 0; fm < 4; fm++) {
    const int rb = m0 + wm * 64 + fm * 16 + lg * 4;
#pragma unroll
    for (int fn = 0; fn < 4; fn++) {
      const int col = n0 + wn * 64 + fn * 16 + lr;
#pragma unroll
      for (int j = 0; j < 4; j++) {
        const size_t idx = (size_t)(rb + j) * N + col;
        if constexpr (EPI == 0) {
          ((float*)Cv)[idx] = acc[fm][fn][j];
        } else if constexpr (EPI == 1) {
          ((__hip_bfloat16*)Cv)[idx] = __float2bfloat16(acc[fm][fn][j]);
        } else {
          const float x = __bfloat162float(G[idx]);
          const float tt = tanhf(0.7978845608028654f * (x + 0.044715f * x * x * x));
          ((__hip_bfloat16*)Cv)[idx] = __float2bfloat16(0.5f * x * (1.f + tt) * acc[fm][fn][j]);
        }
      }
    }
  }
}

// ---------- 8-phase 256x256 bf16 GEMM (r9-proven, B-retention) — used for qkv ----------
// EPI: 4 f32 split: plane0 -> Cv, plane1 -> Cv2
template <int EPI>
__global__ __launch_bounds__(512, 2) void k_gemm8(const __hip_bfloat16* __restrict__ A,
                                                  const __hip_bfloat16* __restrict__ Bt,
                                                  void* __restrict__ Cv,
                                                  const __hip_bfloat16* __restrict__ G,
                                                  const __hip_bfloat16* __restrict__ Bt2,
                                                  void* __restrict__ Cv2,
                                                  int N, int K, int keff) {
  __shared__ alignas(16) __hip_bfloat16 smem[65536];  // 128 KiB
  const int t = threadIdx.x;
  const int w = t >> 6;
  const int wm = w >> 2, wn = w & 3;
  const int l = t & 63;
  const int lr = l & 15, lg = l >> 4;

  const int nxy = gridDim.x * gridDim.y;
  const int nwg = nxy * gridDim.z;
  const int fblk = blockIdx.z * nxy + blockIdx.y * gridDim.x + blockIdx.x;
  const int qq = nwg >> 3, r8 = nwg & 7;
  const int xcd = fblk & 7, ix = fblk >> 3;
  const int swz = (xcd < r8 ? xcd * (qq + 1) : r8 * (qq + 1) + (xcd - r8) * qq) + ix;
  const int plane = swz / nxy;
  const int rem = swz % nxy;
  const int m0 = (rem % gridDim.y) * 256, n0 = (rem / gridDim.y) * 256;
  const int k0 = plane * keff;

  const int sA8 = l & 7;
  size_t aoff[2], boff[2];
#pragma unroll
  for (int j = 0; j < 2; j++) {
    const int rv = (w * 2 + j) * 8 + (l >> 3);
    const int ko = (sA8 ^ (rv & 7)) * 8;
    aoff[j] = (size_t)(m0 + ((rv >> 6) & 1) * 128 + ((rv >> 4) & 3) * 16 + (rv & 15)) * K + k0 + ko;
    boff[j] = (size_t)(n0 + ((rv >> 5) & 3) * 64 + ((rv >> 4) & 1) * 16 + (rv & 15)) * K + k0 + ko;
  }
  const int sl0 = ((lg) ^ (lr & 7)) * 8;
  const int sl1 = ((4 + lg) ^ (lr & 7)) * 8;

  f32x4 acc[8][4];
#pragma unroll
  for (int a = 0; a < 8; a++)
#pragma unroll
    for (int b = 0; b < 4; b++) acc[a][b] = (f32x4){0.f, 0.f, 0.f, 0.f};
  s16x8 af[4][2], bfr[2][2][2];

#define STG_A(bu, h, kti) { _Pragma("unroll") for (int j = 0; j < 2; j++) \
    gload_lds16(A + aoff[j] + (size_t)(h) * 64 * K + (size_t)(kti) * 64, \
                smem + (bu) * 32768 + (h) * 8192 + (w * 2 + j) * 512); }
#define STG_B(bu, h, kti) { _Pragma("unroll") for (int j = 0; j < 2; j++) \
    gload_lds16(Bt + boff[j] + (size_t)(h) * 32 * K + (size_t)(kti) * 64, \
                smem + (bu) * 32768 + 16384 + (h) * 8192 + (w * 2 + j) * 512); }
#define RD_A(bu, fmh) { const __hip_bfloat16* ab_ = smem + (bu) * 32768; \
    _Pragma("unroll") for (int f2 = 0; f2 < 4; f2++) { \
      const int ro_ = ((fmh) * 128 + wm * 64 + f2 * 16 + lr) * 64; \
      af[f2][0] = *(const s16x8*)(ab_ + ro_ + sl0); \
      af[f2][1] = *(const s16x8*)(ab_ + ro_ + sl1); } }
#define RD_BH(bu, fnh) { const __hip_bfloat16* bb_ = smem + (bu) * 32768 + 16384; \
    _Pragma("unroll") for (int f2 = 0; f2 < 2; f2++) { \
      const int ro_ = ((fnh) * 128 + wn * 32 + f2 * 16 + lr) * 64; \
      bfr[fnh][f2][0] = *(const s16x8*)(bb_ + ro_ + sl0); \
      bfr[fnh][f2][1] = *(const s16x8*)(bb_ + ro_ + sl1); } }
#define MFMA16(fmh, fnh) { __builtin_amdgcn_s_setprio(1); \
    _Pragma("unroll") for (int f2 = 0; f2 < 4; f2++) \
    _Pragma("unroll") for (int g2 = 0; g2 < 2; g2++) \
    _Pragma("unroll") for (int ks = 0; ks < 2; ks++) \
      acc[(fmh) * 4 + f2][(fnh) * 2 + g2] = __builtin_amdgcn_mfma_f32_16x16x32_bf16( \
          af[f2][ks], bfr[fnh][g2][ks], acc[(fmh) * 4 + f2][(fnh) * 2 + g2], 0, 0, 0); \
    __builtin_amdgcn_s_setprio(0); }
#define BARR() asm volatile("s_barrier" ::: "memory")
#define LGKM0() asm volatile("s_waitcnt lgkmcnt(0)" ::: "memory")
#define VMC4() asm volatile("s_waitcnt vmcnt(4)" ::: "memory")
#define VMC0() asm volatile("s_waitcnt vmcnt(0)" ::: "memory")

  STG_A(0, 0, 0); STG_A(0, 1, 0); STG_B(0, 0, 0); STG_B(0, 1, 0);
  STG_A(1, 0, 1); STG_A(1, 1, 1);
  VMC4(); BARR();

  const int niter = keff >> 7;
  for (int i = 0; i < niter; ++i) {
    const int t1 = 2 * i + 1;
    const bool more = (i + 1 < niter);
    RD_A(0, 0); RD_BH(0, 0);
    STG_B(1, 0, t1);
    BARR(); LGKM0(); MFMA16(0, 0); BARR();
    RD_BH(0, 1);
    STG_B(1, 1, t1);
    if (more) STG_A(0, 0, t1 + 1);
    BARR(); LGKM0(); MFMA16(0, 1); BARR();
    RD_A(0, 1);
    BARR(); LGKM0(); MFMA16(1, 0); BARR();
    if (more) STG_A(0, 1, t1 + 1);
    BARR(); LGKM0(); MFMA16(1, 1);
    if (more) { VMC4(); } else { VMC0(); }
    BARR();
    RD_A(1, 0); RD_BH(1, 0);
    if (more) STG_B(0, 0, t1 + 1);
    BARR(); LGKM0(); MFMA16(0, 0); BARR();
    RD_BH(1, 1);
    if (more) STG_B(0, 1, t1 + 1);
    BARR(); LGKM0(); MFMA16(0, 1); BARR();
    RD_A(1, 1);
    if (more) STG_A(1, 0, t1 + 2);
    BARR(); LGKM0(); MFMA16(1, 0); BARR();
    if (more) STG_A(1, 1, t1 + 2);
    BARR(); LGKM0(); MFMA16(1, 1);
    if (more) { VMC4(); }
    BARR();
  }
#undef STG_A
#undef STG_B
#undef RD_A
#undef RD_BH
#undef MFMA16
#undef BARR
#undef LGKM0
#undef VMC4
#undef VMC0

#pragma unroll
  for (int fm = 0; fm < 8; fm++) {
    const int rb = m0 + wm * 128 + fm * 16 + lg * 4;
#pragma unroll
    for (int fn = 0; fn < 4; fn++) {
      const int coln = wn * 64 + fn * 16 + lr;
#pragma unroll
      for (int j = 0; j < 4; j++) {
        const size_t idxo = (size_t)(rb + j) * N + n0 + coln;
        if constexpr (EPI == 4) {
          float* P = (plane == 0) ? (float*)Cv : (float*)Cv2;
          P[idxo] = acc[fm][fn][j];
        } else {
          ((__hip_bfloat16*)Cv)[idxo] = __float2bfloat16(acc[fm][fn][j]);
        }
      }
    }
  }
}

// ---------- 8-phase 256x192 bf16 GEMM (BN=192 exact packing; r10-proven) ----------
// EPI: 3 DUAL gate+up; 4 f32 split planes; 5 bf16 split Cv + plane*PSTR.
template <int EPI>
__global__ __launch_bounds__(512, 2) void k_gemm192(const __hip_bfloat16* __restrict__ A,
                                                    const __hip_bfloat16* __restrict__ Bt,
                                                    void* __restrict__ Cv,
                                                    const __hip_bfloat16* __restrict__ Bt2,
                                                    void* __restrict__ Cv2,
                                                    int N, int K, int keff) {
  __shared__ alignas(16) __hip_bfloat16 smem[57344];  // 112 KiB
  const int t = threadIdx.x;
  const int w = t >> 6;
  const int wm = w >> 2, wn = w & 3;
  const int l = t & 63;
  const int lr = l & 15, lg = l >> 4;

  const int nxy = gridDim.x * gridDim.y;
  const int nwg = nxy * gridDim.z;
  const int fblk = blockIdx.z * nxy + blockIdx.y * gridDim.x + blockIdx.x;
  const int qq = nwg >> 3, r8 = nwg & 7;
  const int xcd = fblk & 7, ix = fblk >> 3;
  const int swz = (xcd < r8 ? xcd * (qq + 1) : r8 * (qq + 1) + (xcd - r8) * qq) + ix;
  const int plane = swz / nxy;
  const int rem = swz % nxy;
  const int m0 = (rem % gridDim.y) * 256, n0 = (rem / gridDim.y) * 192;
  const int k0 = plane * keff;

  const __hip_bfloat16* Bsrc = Bt;
  int nb0 = n0;
  if constexpr (EPI == 3) {
    if (n0 >= FFDIM) { Bsrc = Bt2; nb0 = n0 - FFDIM; }
  }

  const int sA8 = l & 7;
  size_t aoff[2];
#pragma unroll
  for (int j = 0; j < 2; j++) {
    const int rv = (w * 2 + j) * 8 + (l >> 3);
    const int ko = (sA8 ^ (rv & 7)) * 8;
    aoff[j] = (size_t)(m0 + ((rv >> 6) & 1) * 128 + ((rv >> 4) & 3) * 16 + (rv & 15)) * K + k0 + ko;
  }
  const size_t boffh = (size_t)(nb0 + w * 8 + (l >> 3)) * K + k0 + ((sA8 ^ (l >> 3)) * 8);
  const int sl0 = ((lg) ^ (lr & 7)) * 8;
  const int sl1 = ((4 + lg) ^ (lr & 7)) * 8;

  f32x4 acc[8][3];
#pragma unroll
  for (int a = 0; a < 8; a++)
#pragma unroll
    for (int b = 0; b < 3; b++) acc[a][b] = (f32x4){0.f, 0.f, 0.f, 0.f};
  s16x8 af[4][2], bfr[3][2];

#define GSTG_A(bu, h, kti) { _Pragma("unroll") for (int j = 0; j < 2; j++) \
    gload_lds16(A + aoff[j] + (size_t)(h) * 64 * K + (size_t)(kti) * 64, \
                smem + (bu) * 28672 + (h) * 8192 + (w * 2 + j) * 512); }
#define GSTG_B(bu, c, kti) \
    gload_lds16(Bsrc + boffh + (size_t)(c) * 64 * K + (size_t)(kti) * 64, \
                smem + (bu) * 28672 + 16384 + ((c) * 64 + w * 8) * 64);
#define GRD_A(bu, fmh) { const __hip_bfloat16* ab_ = smem + (bu) * 28672; \
    _Pragma("unroll") for (int f2 = 0; f2 < 4; f2++) { \
      const int ro_ = ((fmh) * 128 + wm * 64 + f2 * 16 + lr) * 64; \
      af[f2][0] = *(const s16x8*)(ab_ + ro_ + sl0); \
      af[f2][1] = *(const s16x8*)(ab_ + ro_ + sl1); } }
#define GRD_B01(bu) { const __hip_bfloat16* bb_ = smem + (bu) * 28672 + 16384; \
    _Pragma("unroll") for (int f2 = 0; f2 < 2; f2++) { \
      const int ro_ = (wn * 48 + f2 * 16 + lr) * 64; \
      bfr[f2][0] = *(const s16x8*)(bb_ + ro_ + sl0); \
      bfr[f2][1] = *(const s16x8*)(bb_ + ro_ + sl1); } }
#define GRD_B2(bu) { const __hip_bfloat16* bb_ = smem + (bu) * 28672 + 16384; \
      const int ro_ = (wn * 48 + 32 + lr) * 64; \
      bfr[2][0] = *(const s16x8*)(bb_ + ro_ + sl0); \
      bfr[2][1] = *(const s16x8*)(bb_ + ro_ + sl1); }
#define GMFMA01(fmh) { __builtin_amdgcn_s_setprio(1); \
    _Pragma("unroll") for (int f2 = 0; f2 < 4; f2++) \
    _Pragma("unroll") for (int g2 = 0; g2 < 2; g2++) \
    _Pragma("unroll") for (int ks = 0; ks < 2; ks++) \
      acc[(fmh) * 4 + f2][g2] = __builtin_amdgcn_mfma_f32_16x16x32_bf16( \
          af[f2][ks], bfr[g2][ks], acc[(fmh) * 4 + f2][g2], 0, 0, 0); \
    __builtin_amdgcn_s_setprio(0); }
#define GMFMA2(fmh) { __builtin_amdgcn_s_setprio(1); \
    _Pragma("unroll") for (int f2 = 0; f2 < 4; f2++) \
    _Pragma("unroll") for (int ks = 0; ks < 2; ks++) \
      acc[(fmh) * 4 + f2][2] = __builtin_amdgcn_mfma_f32_16x16x32_bf16( \
          af[f2][ks], bfr[2][ks], acc[(fmh) * 4 + f2][2], 0, 0, 0); \
    __builtin_amdgcn_s_setprio(0); }
#define BARR() asm volatile("s_barrier" ::: "memory")
#define LGKM0() asm volatile("s_waitcnt lgkmcnt(0)" ::: "memory")
#define VMC4() asm volatile("s_waitcnt vmcnt(4)" ::: "memory")
#define VMC0() asm volatile("s_waitcnt vmcnt(0)" ::: "memory")

  GSTG_A(0, 0, 0); GSTG_A(0, 1, 0);
  GSTG_B(0, 0, 0); GSTG_B(0, 1, 0); GSTG_B(0, 2, 0);
  GSTG_A(1, 0, 1); GSTG_A(1, 1, 1);
  VMC4(); BARR();

  const int niter = keff >> 7;
  for (int i = 0; i < niter; ++i) {
    const int t1 = 2 * i + 1;
    const bool more = (i + 1 < niter);
    GRD_A(0, 0); GRD_B01(0);
    GSTG_B(1, 0, t1); GSTG_B(1, 1, t1);
    BARR(); LGKM0(); GMFMA01(0); BARR();
    GRD_B2(0);
    GSTG_B(1, 2, t1);
    if (more) GSTG_A(0, 0, t1 + 1);
    BARR(); LGKM0(); GMFMA2(0); BARR();
    GRD_A(0, 1);
    BARR(); LGKM0(); GMFMA01(1); BARR();
    if (more) GSTG_A(0, 1, t1 + 1);
    BARR(); LGKM0(); GMFMA2(1);
    if (more) { VMC4(); } else { VMC0(); }
    BARR();
    GRD_A(1, 0); GRD_B01(1);
    if (more) { GSTG_B(0, 0, t1 + 1); GSTG_B(0, 1, t1 + 1); }
    BARR(); LGKM0(); GMFMA01(0); BARR();
    GRD_B2(1);
    if (more) { GSTG_B(0, 2, t1 + 1); GSTG_A(1, 0, t1 + 2); }
    BARR(); LGKM0(); GMFMA2(0); BARR();
    GRD_A(1, 1);
    BARR(); LGKM0(); GMFMA01(1); BARR();
    if (more) GSTG_A(1, 1, t1 + 2);
    BARR(); LGKM0(); GMFMA2(1);
    if (more) { VMC4(); }
    BARR();
  }
#undef GSTG_A
#undef GSTG_B
#undef GRD_A
#undef GRD_B01
#undef GRD_B2
#undef GMFMA01
#undef GMFMA2
#undef BARR
#undef LGKM0
#undef VMC4
#undef VMC0

  __hip_bfloat16* Cw = nullptr;
  int cbase = n0, cstride = N;
  if constexpr (EPI == 3) {
    Cw = (__hip_bfloat16*)((n0 < FFDIM) ? Cv : Cv2);
    cbase = (n0 < FFDIM) ? n0 : n0 - FFDIM;
    cstride = FFDIM;
  }
#pragma unroll
  for (int fm = 0; fm < 8; fm++) {
    const int rb = m0 + wm * 128 + fm * 16 + lg * 4;
#pragma unroll
    for (int fn = 0; fn < 3; fn++) {
      const int coln = wn * 48 + fn * 16 + lr;
#pragma unroll
      for (int j = 0; j < 4; j++) {
        if constexpr (EPI == 3) {
          Cw[(size_t)(rb + j) * cstride + cbase + coln] = __float2bfloat16(acc[fm][fn][j]);
        } else if constexpr (EPI == 4) {
          float* P = (plane == 0) ? (float*)Cv : (float*)Cv2;
          P[(size_t)(rb + j) * N + n0 + coln] = acc[fm][fn][j];
        } else {
          ((__hip_bfloat16*)Cv)[(size_t)plane * PSTR + (size_t)(rb + j) * N + n0 + coln] =
              __float2bfloat16(acc[fm][fn][j]);
        }
      }
    }
  }
}

// ---------------- gelu(g) * u, all bf16, vectorized x8; o may alias g ----------------
__global__ void k_gelu_mul2(const __hip_bfloat16* __restrict__ g, const __hip_bfloat16* __restrict__ u,
                            __hip_bfloat16* __restrict__ o, int n8) {
  const int st = gridDim.x * blockDim.x;
  for (int i = blockIdx.x * blockDim.x + threadIdx.x; i < n8; i += st) {
    s16x8 gv = *(const s16x8*)(g + (size_t)i * 8);
    s16x8 uv = *(const s16x8*)(u + (size_t)i * 8);
    s16x8 ov;
#pragma unroll
    for (int j = 0; j < 8; j++) {
      const float x = __uint_as_float(((uint32_t)(uint16_t)gv[j]) << 16);
      const float uu = __uint_as_float(((uint32_t)(uint16_t)uv[j]) << 16);
      const float tt = tanhf(0.7978845608028654f * (x + 0.044715f * x * x * x));
      ov[j] = bfr16(0.5f * x * (1.f + tt) * uu);
    }
    *(s16x8*)(o + (size_t)i * 8) = ov;
  }
}

// ------ rope + split + scale (vectorized): qkv = P0+P1 -> Q/K bf16 head-major ------
__global__ void k_rope_split(const float* __restrict__ p0, const float* __restrict__ p1,
                             const float* __restrict__ cosb, const float* __restrict__ sinb,
                             __hip_bfloat16* __restrict__ qo, __hip_bfloat16* __restrict__ ko) {
  const int s = blockIdx.x;
  const float* r0 = p0 + (size_t)s * QKVN;
  const float* r1 = p1 + (size_t)s * QKVN;
  const float* cr = cosb + (size_t)s * 128;
  const float* sr = sinb + (size_t)s * 128;
  for (int idx = threadIdx.x; idx < (NHEAD + NKVH) * 32; idx += 256) {
    const int hh = idx >> 5, d4 = (idx & 31) * 4;
    const float4 c4 = *(const float4*)(cr + d4);
    const float4 s4 = *(const float4*)(sr + d4);
    const int base_in = hh * DHEAD + d4;
    const float4 a1 = *(const float4*)(r0 + base_in);
    const float4 b1 = *(const float4*)(r1 + base_in);
    const float4 a2 = *(const float4*)(r0 + base_in + 128);
    const float4 b2 = *(const float4*)(r1 + base_in + 128);
    const float x1[4] = {a1.x + b1.x, a1.y + b1.y, a1.z + b1.z, a1.w + b1.w};
    const float x2[4] = {a2.x + b2.x, a2.y + b2.y, a2.z + b2.z, a2.w + b2.w};
    const float cc[4] = {c4.x, c4.y, c4.z, c4.w};
    const float ssn[4] = {s4.x, s4.y, s4.z, s4.w};
    const float sc = (hh < NHEAD) ? QSCALE : 1.f;
    s16x4 y1, y2;
#pragma unroll
    for (int j = 0; j < 4; j++) {
      y1[j] = bfr16((x1[j] * cc[j] - x2[j] * ssn[j]) * sc);
      y2[j] = bfr16((x1[j] * ssn[j] + x2[j] * cc[j]) * sc);
    }
    __hip_bfloat16* dst = (hh < NHEAD)
        ? qo + ((size_t)hh * S_LEN + s) * DHEAD
        : ko + ((size_t)(hh - NHEAD) * S_LEN + s) * DHEAD;
    *(s16x4*)(dst + d4) = y1;
    *(s16x4*)(dst + 128 + d4) = y2;
  }
}

// -------- V extract + transpose from 2 partial planes: -> Vt[kv][256 d][2048 s] bf16 --------
__global__ __launch_bounds__(256) void k_vsplit_t(const float* __restrict__ p0,
                                                  const float* __restrict__ p1,
                                                  __hip_bfloat16* __restrict__ vt) {
  __shared__ float tile[64][260];
  const int s0 = blockIdx.x * 64, kv = blockIdx.y;
  const int t = threadIdx.x;
  const int rr = t >> 6, c4 = t & 63;
#pragma unroll
  for (int p = 0; p < 16; p++) {
    const int row = rr + p * 4;
    const size_t go = (size_t)(s0 + row) * QKVN + (NHEAD + NKVH) * DHEAD + kv * DHEAD + c4 * 4;
    const float4 v0 = *(const float4*)(p0 + go);
    const float4 v1 = *(const float4*)(p1 + go);
    float4 v;
    v.x = v0.x + v1.x; v.y = v0.y + v1.y; v.z = v0.z + v1.z; v.w = v0.w + v1.w;
    *(float4*)(&tile[row][c4 * 4]) = v;
  }
  __syncthreads();
  const int c = t & 31, dr = t >> 5;
#pragma unroll
  for (int p = 0; p < 32; p++) {
    const int d = dr + p * 8;
    __hip_bfloat162 pr;
    pr.x = __float2bfloat16(tile[2 * c][d]);
    pr.y = __float2bfloat16(tile[2 * c + 1][d]);
    *(__hip_bfloat162*)(vt + ((size_t)kv * DHEAD + d) * S_LEN + s0 + 2 * c) = pr;
  }
}

// ---------------- MFMA flash attention: sliding-window causal + softcap ----------------
__global__ __launch_bounds__(256) void k_attn_mfma(const __hip_bfloat16* __restrict__ Q,
                                                   const __hip_bfloat16* __restrict__ Kb,
                                                   const __hip_bfloat16* __restrict__ Vt,
                                                   __hip_bfloat16* __restrict__ O) {
  __shared__ alignas(16) __hip_bfloat16 Ks[64 * 264];
  __shared__ alignas(16) __hip_bfloat16 Vs[256 * 72];
  __shared__ alignas(16) __hip_bfloat16 Ps[64 * 72];
  const int h = blockIdx.y, kvh = h >> 1;
  const int q0 = blockIdx.x * 64;
  const int t = threadIdx.x;
  const int wq = t >> 6;
  const int l = t & 63;
  const int lr = l & 15, lg = l >> 4;

  s16x8 qf[8];
  {
    const __hip_bfloat16* qrow = Q + ((size_t)h * S_LEN + q0 + wq * 16 + lr) * DHEAD;
#pragma unroll
    for (int ks = 0; ks < 8; ks++) qf[ks] = *(const s16x8*)(qrow + ks * 32 + lg * 8);
  }
  f32x4 acc[16];
#pragma unroll
  for (int i = 0; i < 16; i++) acc[i] = (f32x4){0.f, 0.f, 0.f, 0.f};
  float rsum[4] = {0.f, 0.f, 0.f, 0.f};

  int lo = q0 - WINM1;
  if (lo < 0) lo = 0;
  lo &= ~63;
  const int qrow_base = q0 + wq * 16 + lg * 4;

  for (int kc = lo; kc <= q0; kc += 64) {
#pragma unroll
    for (int p = 0; p < 8; p++) {
      const int idx = t + p * 256;
      const int row = idx >> 5, c16 = idx & 31;
      s16x8 v = *(const s16x8*)(Kb + ((size_t)kvh * S_LEN + kc + row) * DHEAD + c16 * 8);
      *(s16x8*)(Ks + row * 264 + c16 * 8) = v;
    }
#pragma unroll
    for (int p = 0; p < 8; p++) {
      const int idx = t + p * 256;
      const int d = idx >> 3, ch = idx & 7;
      s16x8 v = *(const s16x8*)(Vt + ((size_t)kvh * DHEAD + d) * S_LEN + kc + ch * 8);
      *(s16x8*)(Vs + d * 72 + ch * 8) = v;
    }
    __syncthreads();

    f32x4 sc[4];
#pragma unroll
    for (int fq = 0; fq < 4; fq++) {
      sc[fq] = (f32x4){0.f, 0.f, 0.f, 0.f};
#pragma unroll
      for (int ks = 0; ks < 8; ks++) {
        s16x8 bfr = *(const s16x8*)(Ks + (fq * 16 + lr) * 264 + ks * 32 + lg * 8);
        sc[fq] = __builtin_amdgcn_mfma_f32_16x16x32_bf16(qf[ks], bfr, sc[fq], 0, 0, 0);
      }
    }
#pragma unroll
    for (int fq = 0; fq < 4; fq++) {
      const int k = kc + fq * 16 + lr;
#pragma unroll
      for (int j = 0; j < 4; j++) {
        const int qw = qrow_base + j;
        float p = 0.f;
        if (k <= qw && qw - k <= WINM1) {
          const float s = sc[fq][j];
          const float u = exp2f(s * 0.057707801635558534f);
          const float arg = 72.134752044448169f -
                            144.26950408889634f * __builtin_amdgcn_rcpf(u + 1.f);
          p = exp2f(arg);
        }
        const __hip_bfloat16 pb = __float2bfloat16(p);
        Ps[(wq * 16 + lg * 4 + j) * 72 + fq * 16 + lr] = pb;
        rsum[j] += __bfloat162float(pb);
      }
    }
#pragma unroll
    for (int ks2 = 0; ks2 < 2; ks2++) {
      s16x8 pa = *(const s16x8*)(Ps + (wq * 16 + lr) * 72 + ks2 * 32 + lg * 8);
#pragma unroll
      for (int f2 = 0; f2 < 16; f2++) {
        s16x8 vb = *(const s16x8*)(Vs + (f2 * 16 + lr) * 72 + ks2 * 32 + lg * 8);
        acc[f2] = __builtin_amdgcn_mfma_f32_16x16x32_bf16(pa, vb, acc[f2], 0, 0, 0);
      }
    }
    __syncthreads();
  }
#pragma unroll
  for (int j = 0; j < 4; j++) {
    float s = rsum[j];
#pragma unroll
    for (int off = 1; off < 16; off <<= 1) s += __shfl_xor(s, off, 64);
    rsum[j] = 1.f / s;
  }
#pragma unroll
  for (int f2 = 0; f2 < 16; f2++)
#pragma unroll
    for (int j = 0; j < 4; j++)
      O[(size_t)(qrow_base + j) * ODIM + h * DHEAD + f2 * 16 + lr] =
          __float2bfloat16(acc[f2][j] * rsum[j]);
}

// ---------------- launcher ----------------
extern "C" void kernel_launch(void* const* d_in, const int* in_sizes, int n_in,
                              void* d_out, int out_size, void* d_ws, size_t ws_size,
                              hipStream_t stream) {
  const float* hidden  = (const float*)d_in[0];
  const float* qkv_w   = (const float*)d_in[1];
  const float* o_w     = (const float*)d_in[2];
  const float* gate_w  = (const float*)d_in[3];
  const float* up_w    = (const float*)d_in[4];
  const float* down_w  = (const float*)d_in[5];
  const float* in_ln   = (const float*)d_in[6];
  const float* post_attn_ln = (const float*)d_in[7];
  const float* pre_ffw_ln   = (const float*)d_in[8];
  const float* post_ffw_ln  = (const float*)d_in[9];
  const float* cosb    = (const float*)d_in[10];
  const float* sinb    = (const float*)d_in[11];
  float* out = (float*)d_out;
  char* ws = (char*)d_ws;

  const size_t OFF_W   = 0;
  const size_t OFF_HF  = 42467328;
  const size_t OFF_X   = 61341696;
  const size_t OFF_S1  = 70778880;
  const size_t OFF_S2  = 108527616;
  const size_t NEED    = 146276352;
  const size_t OFF_W2  = 146276352;
  const size_t NEED_F  = 188743680;

  if (ws_size < NEED) {
    k_fill<<<1024, 256, 0, stream>>>(out, 100000.0f + (float)(ws_size >> 20), (size_t)out_size);
    return;
  }
  const bool FUSED = (ws_size >= NEED_F);

  __hip_bfloat16* W    = (__hip_bfloat16*)(ws + OFF_W);
  __hip_bfloat16* W2   = (__hip_bfloat16*)(ws + OFF_W2);
  float*          Hf   = (float*)(ws + OFF_HF);
  __hip_bfloat16* Xb   = (__hip_bfloat16*)(ws + OFF_X);
  __hip_bfloat16* GATEB= (__hip_bfloat16*)(ws + OFF_S1);
  __hip_bfloat16* UPB  = (__hip_bfloat16*)(ws + OFF_S2);
  __hip_bfloat16* Qb   = (__hip_bfloat16*)(ws + OFF_S2);
  __hip_bfloat16* Kb   = (__hip_bfloat16*)(ws + OFF_S2 + 8388608);
  __hip_bfloat16* Vtb  = (__hip_bfloat16*)(ws + OFF_S2 + 12582912);
  __hip_bfloat16* ATTN = (__hip_bfloat16*)(ws + OFF_S2 + 29360128);

  if (FUSED) {
    float* QKV0 = (float*)(ws + OFF_S1);
    float* QKV1 = (float*)(ws + OFF_W2);
    float* PROJ = (float*)(ws + OFF_S1);
    __hip_bfloat16* DPART = (__hip_bfloat16*)(ws + OFF_S2);

    // 1. qkv^T -> W ; x = rmsnorm(hidden) -> Xb ; qkv = Xb @ W^T (256^2 8-phase, split-K=2)
    k_transpose_bf16<<<dim3(QKVN / 64, HIDDEN / 32), 256, 0, stream>>>(qkv_w, W, HIDDEN, QKVN);
    k_rmsnorm<1, false, false, true><<<S_LEN, 256, 0, stream>>>(hidden, in_ln, nullptr, Xb);
    k_gemm8<4><<<dim3(QKVN / 256, S_LEN / 256, 2), 512, 0, stream>>>(
        Xb, W, QKV0, nullptr, nullptr, QKV1, QKVN, HIDDEN, HIDDEN / 2);
    // 2. rope+split Q/K ; V extract+transpose
    k_rope_split<<<S_LEN, 256, 0, stream>>>(QKV0, QKV1, cosb, sinb, Qb, Kb);
    k_vsplit_t<<<dim3(S_LEN / 64, NKVH), 256, 0, stream>>>(QKV0, QKV1, Vtb);
    // 3. attention -> ATTN (bf16)
    k_attn_mfma<<<dim3(S_LEN / 64, NHEAD), 256, 0, stream>>>(Qb, Kb, Vtb, ATTN);
    // 4. o^T -> W ; proj = ATTN @ W^T (192-col 8-phase, split-K=2 -> 192 blocks, 1 round)
    k_transpose_bf16<<<dim3(HIDDEN / 64, ODIM / 32), 256, 0, stream>>>(o_w, W, ODIM, HIDDEN);
    k_gemm192<4><<<dim3(HIDDEN / 192, S_LEN / 256, 2), 512, 0, stream>>>(
        ATTN, W, PROJ, nullptr, PROJ + PSTR, HIDDEN, ODIM, ODIM / 2);
    // 5. fused double rmsnorm
    k_rmsnorm2<<<S_LEN, 256, 0, stream>>>(PROJ, post_attn_ln, hidden, pre_ffw_ln, Hf, Xb);
    // 6. gate^T -> W, up^T -> W2; fused gate+up GEMM (768 blocks = exactly 3 rounds)
    k_transpose_bf16<<<dim3(FFDIM / 64, HIDDEN / 32), 256, 0, stream>>>(gate_w, W, HIDDEN, FFDIM);
    k_transpose_bf16<<<dim3(FFDIM / 64, HIDDEN / 32), 256, 0, stream>>>(up_w, W2, HIDDEN, FFDIM);
    k_gemm192<3><<<dim3((2 * FFDIM) / 192, S_LEN / 256, 1), 512, 0, stream>>>(
        Xb, W, GATEB, W2, UPB, FFDIM, HIDDEN, HIDDEN);
    // 7. act = gelu(gate)*up, in-place over S1
    k_gelu_mul2<<<2048, 256, 0, stream>>>(GATEB, UPB, GATEB, (S_LEN * FFDIM) / 8);
    // 8. down^T -> W ; y-partials (split-K=8, 768 blocks = 3 rounds, bf16 planes)
    k_transpose_bf16<<<dim3(HIDDEN / 64, FFDIM / 32), 256, 0, stream>>>(down_w, W, FFDIM, HIDDEN);
    k_gemm192<5><<<dim3(HIDDEN / 192, S_LEN / 256, 8), 512, 0, stream>>>(
        GATEB, W, DPART, nullptr, nullptr, HIDDEN, FFDIM, FFDIM / 8);
    // 9. out = h + rmsnorm(sum of 8 partials)
    k_rmsnorm<8, true, true, false><<<S_LEN, 256, 0, stream>>>(DPART, post_ffw_ln, Hf, out);
  } else {
    // fallback: no split-K (zero plane1 via Hf)
    float* QKV = (float*)(ws + OFF_S1);
    float* PROJ = (float*)(ws + OFF_S2);
    k_transpose_bf16<<<dim3(QKVN / 64, HIDDEN / 32), 256, 0, stream>>>(qkv_w, W, HIDDEN, QKVN);
    k_rmsnorm<1, false, false, true><<<S_LEN, 256, 0, stream>>>(hidden, in_ln, nullptr, Xb);
    k_gemm_bt<0><<<dim3(QKVN / 128, S_LEN / 128), 256, 0, stream>>>(Xb, W, QKV, nullptr, QKVN, HIDDEN);
    k_fill<<<1024, 256, 0, stream>>>(Hf, 0.f, PSTR);
    k_rope_split<<<S_LEN, 256, 0, stream>>>(QKV, Hf, cosb, sinb, Qb, Kb);
    k_vsplit_t<<<dim3(S_LEN / 64, NKVH), 256, 0, stream>>>(QKV, Hf, Vtb);
    k_attn_mfma<<<dim3(S_LEN / 64, NHEAD), 256, 0, stream>>>(Qb, Kb, Vtb, ATTN);
    k_transpose_bf16<<<dim3(HIDDEN / 64, ODIM / 32), 256, 0, stream>>>(o_w, W, ODIM, HIDDEN);
    k_gemm_bt<0><<<dim3(HIDDEN / 128, S_LEN / 128), 256, 0, stream>>>(ATTN, W, PROJ, nullptr, HIDDEN, ODIM);
    k_rmsnorm<1, false, true, false><<<S_LEN, 256, 0, stream>>>(PROJ, post_attn_ln, hidden, Hf);
    k_rmsnorm<1, false, false, true><<<S_LEN, 256, 0, stream>>>(Hf, pre_ffw_ln, nullptr, Xb);
    k_transpose_bf16<<<dim3(FFDIM / 64, HIDDEN / 32), 256, 0, stream>>>(gate_w, W, HIDDEN, FFDIM);
    k_gemm_bt<1><<<dim3(FFDIM / 128, S_LEN / 128), 256, 0, stream>>>(Xb, W, GATEB, nullptr, FFDIM, HIDDEN);
    __hip_bfloat16* ACT = (__hip_bfloat16*)(ws + OFF_S2);
    k_transpose_bf16<<<dim3(FFDIM / 64, HIDDEN / 32), 256, 0, stream>>>(up_w, W, HIDDEN, FFDIM);
    k_gemm_bt<2><<<dim3(FFDIM / 128, S_LEN / 128), 256, 0, stream>>>(Xb, W, ACT, GATEB, FFDIM, HIDDEN);
    float* Yf = (float*)(ws + OFF_S1);
    k_transpose_bf16<<<dim3(HIDDEN / 64, FFDIM / 32), 256, 0, stream>>>(down_w, W, FFDIM, HIDDEN);
    k_gemm_bt<0><<<dim3(HIDDEN / 128, S_LEN / 128), 256, 0, stream>>>(ACT, W, Yf, nullptr, HIDDEN, FFDIM);
    k_rmsnorm<1, false, true, false><<<S_LEN, 256, 0, stream>>>(Yf, post_ffw_ln, Hf, out);
  }
}